// Round 14
// baseline (617.498 us; speedup 1.0000x reference)
//
#include <hip/hip_runtime.h>
#include <stdint.h>

typedef unsigned short u16;
typedef __bf16 bf16x8 __attribute__((ext_vector_type(8)));
typedef unsigned short u16x8 __attribute__((ext_vector_type(8)));
typedef unsigned short u16x4 __attribute__((ext_vector_type(4)));
typedef float f32x4 __attribute__((ext_vector_type(4)));

#define B_ 2
#define S_ 2048
#define HID_ 4096
#define NH_ 32
#define NKV_ 8
#define HD_ 128
#define NTOT_ 6144
#define SCALE_ 0.08838834764831845f

#define GLD16(gp, lp)                                                     \
  __builtin_amdgcn_global_load_lds(                                       \
      (__attribute__((address_space(1))) void*)(gp),                      \
      (__attribute__((address_space(3))) void*)(lp), 16, 0, 0)

#define BAR __builtin_amdgcn_s_barrier()
#define PRIO1 __builtin_amdgcn_s_setprio(1)
#define PRIO0 __builtin_amdgcn_s_setprio(0)
#define VM4 asm volatile("s_waitcnt vmcnt(4)" ::: "memory")
#define VM0 asm volatile("s_waitcnt vmcnt(0)" ::: "memory")

// ---------- bf16 helpers ----------
__device__ __forceinline__ u16 f2b(float f) {
  union { float f; uint32_t u; } v; v.f = f;
  uint32_t u = v.u;
  u = u + 0x7fffu + ((u >> 16) & 1u);
  return (u16)(u >> 16);
}
__device__ __forceinline__ float b2f(u16 s) {
  union { uint32_t u; float f; } v; v.u = ((uint32_t)s) << 16;
  return v.f;
}
__device__ __forceinline__ bf16x8 ldb8(const u16* p) {
  u16x8 u = *(const u16x8*)p;
  return __builtin_bit_cast(bf16x8, u);
}
__device__ __forceinline__ bf16x8 ldb8b(const char* p) {
  u16x8 u = *(const u16x8*)p;
  return __builtin_bit_cast(bf16x8, u);
}

// ---------- kernel 1: f32 -> bf16 ----------
__global__ __launch_bounds__(256) void k_convx(const float* __restrict__ src,
                                               u16* __restrict__ dst, int n4) {
  int i = blockIdx.x * 256 + threadIdx.x;
  if (i >= n4) return;
  const float4 v = ((const float4*)src)[i];
  u16x4 o = { f2b(v.x), f2b(v.y), f2b(v.z), f2b(v.w) };
  *(u16x4*)(dst + (size_t)i * 4) = o;
}

// ---------- kernel 2a: transpose-convert Wo f32 [Kd][N] -> bf16 [N][Kd] ----------
__global__ __launch_bounds__(256) void k_convT(const float* __restrict__ src,
                                               u16* __restrict__ dst, int N, int Kd) {
  __shared__ u16 tile[64][65];
  int k0 = blockIdx.x * 64, n0 = blockIdx.y * 64;
  int t = threadIdx.x;
  int rr = t >> 4;
  int cc = (t & 15) * 4;
#pragma unroll
  for (int p = 0; p < 4; ++p) {
    int r = p * 16 + rr;
    float4 v = *(const float4*)&src[(size_t)(k0 + r) * N + n0 + cc];
    tile[cc + 0][r] = f2b(v.x);
    tile[cc + 1][r] = f2b(v.y);
    tile[cc + 2][r] = f2b(v.z);
    tile[cc + 3][r] = f2b(v.w);
  }
  __syncthreads();
#pragma unroll
  for (int p = 0; p < 4; ++p) {
    int n = p * 16 + rr;
    u16x4 o = { tile[n][cc], tile[n][cc + 1], tile[n][cc + 2], tile[n][cc + 3] };
    *(u16x4*)&dst[(size_t)(n0 + n) * Kd + k0 + cc] = o;
  }
}

// ---------- kernel 2b: merged Wq|Wk|Wv transpose-convert -> WqkvT [6144][4096] ----------
__global__ __launch_bounds__(256) void k_convqkv(const float* __restrict__ Wq,
                                                 const float* __restrict__ Wk,
                                                 const float* __restrict__ Wv,
                                                 u16* __restrict__ dst) {
  __shared__ u16 tile[64][65];
  const int Kd = HID_;
  int k0 = blockIdx.x * 64;
  int ng = blockIdx.y * 64;
  const float* src;
  int N, ns;
  if (ng < 4096)      { src = Wq; N = 4096; ns = ng; }
  else if (ng < 5120) { src = Wk; N = 1024; ns = ng - 4096; }
  else                { src = Wv; N = 1024; ns = ng - 5120; }
  int t = threadIdx.x;
  int rr = t >> 4;
  int cc = (t & 15) * 4;
#pragma unroll
  for (int p = 0; p < 4; ++p) {
    int r = p * 16 + rr;
    float4 v = *(const float4*)&src[(size_t)(k0 + r) * N + ns + cc];
    tile[cc + 0][r] = f2b(v.x);
    tile[cc + 1][r] = f2b(v.y);
    tile[cc + 2][r] = f2b(v.z);
    tile[cc + 3][r] = f2b(v.w);
  }
  __syncthreads();
#pragma unroll
  for (int p = 0; p < 4; ++p) {
    int n = p * 16 + rr;
    u16x4 o = { tile[n][cc], tile[n][cc + 1], tile[n][cc + 2], tile[n][cc + 3] };
    *(u16x4*)&dst[(size_t)(ng + n) * Kd + k0 + cc] = o;
  }
}

// ---------- out-proj GEMM: 256x256, BK=64, cross-phase reg-pipelined ----------
// Phase p=(kt,kc): [stage(kt+1,kc) ; vmcnt(4) ; BAR ; read frags for p+1 (set Y) ;
// MFMA with set X read during p-1]. MFMA has no dependency on this phase's reads
// -> reads drain in the MFMA shadow (the overlap R8-R11 lacked). 1 BAR/phase.
// Ledger: VM4@p retires exactly the 4 loads read this phase; stages write the
// opposite buffer of any in-flight read; region overwrite happens >=1 barrier
// after all waves' reads of it are lgkm-complete (consumed by an MFMA before
// the wave passed the preceding barrier). Tail: phase A VM0, phase B empty queue.
__global__ __launch_bounds__(512) void k_gemm_out(const u16* __restrict__ A,
                                                  const u16* __restrict__ Bt,
                                                  float* __restrict__ Cf,
                                                  int M, int N, int Kd) {
  __shared__ __align__(16) char smem[131072];
  const int NT = Kd >> 6;

  int nwg = gridDim.x * gridDim.y;
  int orig = blockIdx.y * gridDim.x + blockIdx.x;
  int cpx = nwg >> 3;
  int swz = (orig & 7) * cpx + (orig >> 3);
  int bx = swz % gridDim.x, by = swz / gridDim.x;
  int m0 = by * 256, n0 = bx * 256;

  int t = threadIdx.x, lane = t & 63, wave = t >> 6;
  int wr = wave >> 2, wc = wave & 3;
  int lg = lane >> 4, l16 = lane & 15;
  int loff = l16 * 64 + ((lg ^ ((l16 >> 1) & 3)) << 4);
  int srow = lane >> 2, schk = (lane & 3) ^ ((lane >> 3) & 3);

  const u16* Asrc = A  + (size_t)(m0 + wave * 32 + srow) * Kd + schk * 8;
  const u16* Bsrc = Bt + (size_t)(n0 + wave * 32 + srow) * Kd + schk * 8;

  f32x4 acc[8][4] = {};

#define OSTG(tile, kc) do {                                                   \
    int BB_ = ((tile) & 1) << 16;                                             \
    char* dA_ = smem + BB_ + ((kc) << 14) + (wave << 11);                     \
    const u16* sA_ = Asrc + (size_t)(tile) * 64 + (kc) * 32;                  \
    GLD16(sA_, dA_); GLD16(sA_ + (size_t)16 * Kd, dA_ + 1024);                \
    char* dB_ = smem + BB_ + 32768 + ((kc) << 14) + (wave << 11);             \
    const u16* sB_ = Bsrc + (size_t)(tile) * 64 + (kc) * 32;                  \
    GLD16(sB_, dB_); GLD16(sB_ + (size_t)16 * Kd, dB_ + 1024); } while (0)
#define OREAD(S, bb, kc) do { _Pragma("unroll")                               \
    for (int j = 0; j < 4; ++j)                                               \
      S##b_[j] = ldb8b(smem + (bb) + 32768 + ((kc) << 14) + ((wc * 4 + j) << 10) + loff); \
    _Pragma("unroll")                                                         \
    for (int i = 0; i < 4; ++i)                                               \
      S##a0[i] = ldb8b(smem + (bb) + ((kc) << 14) + ((wr * 8 + i) << 10) + loff); \
    _Pragma("unroll")                                                         \
    for (int i = 0; i < 4; ++i)                                               \
      S##a1[i] = ldb8b(smem + (bb) + ((kc) << 14) + ((wr * 8 + 4 + i) << 10) + loff); } while (0)
#define OMM(S) do { PRIO1; _Pragma("unroll")                                  \
    for (int i = 0; i < 4; ++i) { _Pragma("unroll")                           \
      for (int j = 0; j < 4; ++j)                                             \
        acc[i][j] = __builtin_amdgcn_mfma_f32_16x16x32_bf16(S##a0[i], S##b_[j], acc[i][j], 0, 0, 0); } \
    _Pragma("unroll")                                                         \
    for (int i = 0; i < 4; ++i) { _Pragma("unroll")                           \
      for (int j = 0; j < 4; ++j)                                             \
        acc[4 + i][j] = __builtin_amdgcn_mfma_f32_16x16x32_bf16(S##a1[i], S##b_[j], acc[4 + i][j], 0, 0, 0); } \
    PRIO0; } while (0)

  bf16x8 Xb_[4], Xa0[4], Xa1[4], Yb_[4], Ya0[4], Ya1[4];

  // prologue: tile 0 both halves (8 loads); retire kc0; read set X for phase 0
  OSTG(0, 0); OSTG(0, 1);
  VM4; BAR;
  OREAD(X, 0, 0);

  for (int kt = 0; kt < NT; ++kt) {
    int bb = (kt & 1) << 16;
    bool pf = (kt + 1 < NT);
    // phase A: MFMA (kt,kc0) from X; prefetch (kt,kc1) into Y
    if (pf) { OSTG(kt + 1, 0); VM4; } else { VM0; }
    BAR;
    OREAD(Y, bb, 1);
    OMM(X);
    // phase B: MFMA (kt,kc1) from Y; prefetch (kt+1,kc0) into X
    if (pf) { OSTG(kt + 1, 1); VM4; }
    BAR;
    if (pf) OREAD(X, ((kt + 1) & 1) << 16, 0);
    OMM(Y);
  }
#undef OSTG
#undef OREAD
#undef OMM

#pragma unroll
  for (int i = 0; i < 8; ++i)
#pragma unroll
    for (int j = 0; j < 4; ++j)
#pragma unroll
      for (int r = 0; r < 4; ++r) {
        int m = m0 + wr * 128 + i * 16 + lg * 4 + r;
        int n = n0 + wc * 64 + j * 16 + l16;
        Cf[(size_t)m * N + n] = acc[i][j][r];
      }
}

// ---------- QKV GEMM: 256x192, BK=64, same cross-phase reg pipeline ----------
// Stage = 4 loads/wave/phase (A 2 + B 2; B's high groups duplicated by waves
// 4-7 with identical bytes -> benign; keeps VM4 arithmetic uniform).
__global__ __launch_bounds__(512) void k_gqkv(const u16* __restrict__ A,
                                              const u16* __restrict__ Bt,
                                              u16* __restrict__ Qb,
                                              u16* __restrict__ Kb,
                                              u16* __restrict__ Vb) {
  __shared__ __align__(16) char smem[114688];
  const int Kd = HID_;
  const int NT = Kd >> 6;

  // grid 32x16 = 512, cpx = 64
  int orig = blockIdx.y * 32 + blockIdx.x;
  int swz = (orig & 7) * 64 + (orig >> 3);
  int bx = swz & 31, by = swz >> 5;
  int m0 = by * 256, n0 = bx * 192;

  int t = threadIdx.x, lane = t & 63, wave = t >> 6;
  int wr = wave >> 2, wc = wave & 3;
  int lg = lane >> 4, l16 = lane & 15;
  int loff = l16 * 64 + ((lg ^ ((l16 >> 1) & 3)) << 4);
  int srow = lane >> 2, schk = (lane & 3) ^ ((lane >> 3) & 3);

  const u16* Asrc = A + (size_t)(m0 + wave * 32 + srow) * Kd + schk * 8;
  const u16* sB0 = Bt + (size_t)(n0 + wave * 16 + srow) * Kd + schk * 8;
  const u16* sB1 = Bt + (size_t)(n0 + 128 + (wave & 3) * 16 + srow) * Kd + schk * 8;
  int bdst2 = (8 + (wave & 3)) << 10;

  f32x4 acc[8][3] = {};

#define QSTG(tile, kc) do {                                                   \
    int BB_ = ((tile) & 1) * 57344;                                           \
    char* dA_ = smem + BB_ + ((kc) << 14) + (wave << 11);                     \
    const u16* sA_ = Asrc + (size_t)(tile) * 64 + (kc) * 32;                  \
    GLD16(sA_, dA_); GLD16(sA_ + (size_t)16 * Kd, dA_ + 1024);                \
    char* dB_ = smem + BB_ + 32768 + (kc) * 12288;                            \
    GLD16(sB0 + (size_t)(tile) * 64 + (kc) * 32, dB_ + (wave << 10));         \
    GLD16(sB1 + (size_t)(tile) * 64 + (kc) * 32, dB_ + bdst2); } while (0)
#define QREAD(S, bb, kc) do { _Pragma("unroll")                               \
    for (int j = 0; j < 3; ++j)                                               \
      S##b_[j] = ldb8b(smem + (bb) + 32768 + (kc) * 12288 + ((wc * 3 + j) << 10) + loff); \
    _Pragma("unroll")                                                         \
    for (int i = 0; i < 4; ++i)                                               \
      S##a0[i] = ldb8b(smem + (bb) + ((kc) << 14) + ((wr * 8 + i) << 10) + loff); \
    _Pragma("unroll")                                                         \
    for (int i = 0; i < 4; ++i)                                               \
      S##a1[i] = ldb8b(smem + (bb) + ((kc) << 14) + ((wr * 8 + 4 + i) << 10) + loff); } while (0)
#define QMM(S) do { PRIO1; _Pragma("unroll")                                  \
    for (int i = 0; i < 4; ++i) { _Pragma("unroll")                           \
      for (int j = 0; j < 3; ++j)                                             \
        acc[i][j] = __builtin_amdgcn_mfma_f32_16x16x32_bf16(S##a0[i], S##b_[j], acc[i][j], 0, 0, 0); } \
    _Pragma("unroll")                                                         \
    for (int i = 0; i < 4; ++i) { _Pragma("unroll")                           \
      for (int j = 0; j < 3; ++j)                                             \
        acc[4 + i][j] = __builtin_amdgcn_mfma_f32_16x16x32_bf16(S##a1[i], S##b_[j], acc[4 + i][j], 0, 0, 0); } \
    PRIO0; } while (0)

  bf16x8 Xb_[3], Xa0[4], Xa1[4], Yb_[3], Ya0[4], Ya1[4];

  QSTG(0, 0); QSTG(0, 1);
  VM4; BAR;
  QREAD(X, 0, 0);

  for (int kt = 0; kt < NT; ++kt) {
    int bb = (kt & 1) * 57344;
    bool pf = (kt + 1 < NT);
    // phase A
    if (pf) { QSTG(kt + 1, 0); VM4; } else { VM0; }
    BAR;
    QREAD(Y, bb, 1);
    QMM(X);
    // phase B
    if (pf) { QSTG(kt + 1, 1); VM4; }
    BAR;
    if (pf) QREAD(X, ((kt + 1) & 1) * 57344, 0);
    QMM(Y);
  }
#undef QSTG
#undef QREAD
#undef QMM

  // epilogue: per-element head/d (192-wide N slice crosses head boundaries)
#pragma unroll
  for (int i = 0; i < 8; ++i)
#pragma unroll
    for (int j = 0; j < 3; ++j)
#pragma unroll
      for (int r = 0; r < 4; ++r) {
        int m = m0 + wr * 128 + i * 16 + lg * 4 + r;
        int n = n0 + wc * 48 + j * 16 + l16;
        int head = n >> 7, d = n & 127;
        int b = m >> 11, s = m & (S_ - 1);
        u16 val = f2b(acc[i][j][r]);
        if (head < NH_) {
          Qb[(((size_t)b * NH_ + head) * S_ + s) * HD_ + d] = val;
        } else if (head < NH_ + NKV_) {
          Kb[(((size_t)b * NKV_ + (head - NH_)) * S_ + s) * HD_ + d] = val;
        } else {
          Vb[(((size_t)b * NKV_ + (head - NH_ - NKV_)) * HD_ + d) * S_ + s] = val;
        }
      }
}

// ---------- kernel 4: merged RoPE (Q rows then K rows), one launch ----------
__global__ __launch_bounds__(256) void k_rope2(u16* __restrict__ Qb, u16* __restrict__ Kb,
                                               const int* __restrict__ pos,
                                               const float* __restrict__ ct,
                                               const float* __restrict__ st) {
  int wave = threadIdx.x >> 6, lane = threadIdx.x & 63;
  int row = blockIdx.x * 4 + wave;
  u16* buf;
  int H;
  if (row < B_ * NH_ * S_) { buf = Qb; H = NH_; }
  else { buf = Kb; H = NKV_; row -= B_ * NH_ * S_; }
  int s = row & (S_ - 1);
  int b = row / (H * S_);
  int p = pos[b * S_ + s];
  size_t base = (size_t)row * HD_;
  float x1 = b2f(buf[base + lane]);
  float x2 = b2f(buf[base + 64 + lane]);
  float c  = ct[(size_t)p * HD_ + lane];
  float sn = st[(size_t)p * HD_ + lane];
  buf[base + lane]      = f2b(x1 * c - x2 * sn);
  buf[base + 64 + lane] = f2b(x2 * c + x1 * sn);
}

// ---------- kernel 5: causal GQA flash attention (unchanged) ----------
__global__ __launch_bounds__(256, 4) void k_attn(const u16* __restrict__ Q,
                                                 const u16* __restrict__ K,
                                                 const u16* __restrict__ Vt,
                                                 u16* __restrict__ Ob) {
  __shared__ __align__(16) char smem[40960];
  const int VS_OFF = 16384, PS_OFF = 32768;

  int bid = blockIdx.x;
  int pid = bid & 15;
  int h   = (bid >> 4) & 31;
  int b   = bid >> 9;
  int kvh = h >> 2;
  int tid = threadIdx.x;
  int wave = tid >> 6, lane = tid & 63;
  int lg = lane >> 4, l16 = lane & 15;
  int lsw = (l16 & 7) << 4;

  const u16* Qp = Q  + (((size_t)b * NH_  + h)   * S_) * HD_;
  const u16* Kp = K  + (((size_t)b * NKV_ + kvh) * S_) * HD_;
  const u16* Vp = Vt + (((size_t)b * NKV_ + kvh) * HD_) * S_;

  for (int pass = 0; pass < 2; ++pass) {
    int qt = pass ? (31 - pid) : pid;
    int q0 = qt * 64 + wave * 16;
    int qg = q0 + l16;

    bf16x8 qf[4];
#pragma unroll
    for (int c = 0; c < 4; ++c)
      qf[c] = ldb8(&Qp[(size_t)qg * HD_ + c * 32 + lg * 8]);

    f32x4 oacc[8] = {};
    float mrun = -1e30f, lrun = 0.f;

    int nt = qt + 1;
    for (int tI = 0; tI < nt; ++tI) {
      int kb = tI * 64;
      __syncthreads();
#pragma unroll
      for (int i = 0; i < 4; ++i) {
        int ci = i * 256 + tid;
        int r = ci >> 4, ch = ci & 15;
        u16x8 v = *(const u16x8*)&Kp[(size_t)(kb + r) * HD_ + ch * 8];
        *(u16x8*)(smem + r * 256 + ((ch * 16) ^ ((r & 7) << 4))) = v;
      }
#pragma unroll
      for (int i = 0; i < 4; ++i) {
        int ci = i * 256 + tid;
        int r = ci >> 3, ch = ci & 7;
        u16x8 v = *(const u16x8*)&Vp[(size_t)r * S_ + kb + ch * 8];
        *(u16x8*)(smem + VS_OFF + r * 128 + ((ch * 16) ^ ((r & 7) << 4))) = v;
      }
      __syncthreads();

      f32x4 sc[4] = {};
#pragma unroll
      for (int c = 0; c < 4; ++c) {
#pragma unroll
        for (int n = 0; n < 4; ++n) {
          bf16x8 kf = ldb8b(smem + (n * 16 + l16) * 256 + ((c * 64 + lg * 16) ^ lsw));
          sc[n] = __builtin_amdgcn_mfma_f32_16x16x32_bf16(kf, qf[c], sc[n], 0, 0, 0);
        }
      }

      bool diag = (tI == qt);
      float mx = -1e30f;
#pragma unroll
      for (int n = 0; n < 4; ++n)
#pragma unroll
        for (int r = 0; r < 4; ++r) {
          float v = sc[n][r];
          int key = kb + n * 16 + lg * 4 + r;
          if (diag && key > qg) v = -1e30f;
          sc[n][r] = v;
          mx = fmaxf(mx, v);
        }
      mx = fmaxf(mx, __shfl_xor(mx, 16));
      mx = fmaxf(mx, __shfl_xor(mx, 32));
      float mnew = fmaxf(mrun, mx * SCALE_);
      float alpha = __expf(mrun - mnew);
      float ps = 0.f;
#pragma unroll
      for (int n = 0; n < 4; ++n) {
        u16x4 pk;
#pragma unroll
        for (int r = 0; r < 4; ++r) {
          float p = __expf(fmaf(sc[n][r], SCALE_, -mnew));
          ps += p;
          pk[r] = f2b(p);
        }
        *(u16x4*)(smem + PS_OFF + wave * 2048 + l16 * 128 + ((n * 32 + lg * 8) ^ lsw)) = pk;
      }
      ps += __shfl_xor(ps, 16);
      ps += __shfl_xor(ps, 32);
      lrun = lrun * alpha + ps;
      mrun = mnew;

      float ar[4];
#pragma unroll
      for (int r = 0; r < 4; ++r) ar[r] = __shfl(alpha, lg * 4 + r);
#pragma unroll
      for (int ns = 0; ns < 8; ++ns)
#pragma unroll
        for (int r = 0; r < 4; ++r) oacc[ns][r] *= ar[r];

#pragma unroll
      for (int ck = 0; ck < 2; ++ck) {
        bf16x8 pa = ldb8b(smem + PS_OFF + wave * 2048 + l16 * 128 + ((ck * 64 + lg * 16) ^ lsw));
#pragma unroll
        for (int ns = 0; ns < 8; ++ns) {
          bf16x8 vf = ldb8b(smem + VS_OFF + (ns * 16 + l16) * 128 + ((ck * 64 + lg * 16) ^ lsw));
          oacc[ns] = __builtin_amdgcn_mfma_f32_16x16x32_bf16(pa, vf, oacc[ns], 0, 0, 0);
        }
      }
    }

    float lr[4];
#pragma unroll
    for (int r = 0; r < 4; ++r) lr[r] = 1.0f / __shfl(lrun, lg * 4 + r);
#pragma unroll
    for (int ns = 0; ns < 8; ++ns)
#pragma unroll
      for (int r = 0; r < 4; ++r) {
        int q = q0 + lg * 4 + r;
        Ob[((size_t)(b * S_) + q) * (NH_ * HD_) + h * HD_ + ns * 16 + l16] =
            f2b(oacc[ns][r] * lr[r]);
      }
  }
}

// ---------- launch ----------
extern "C" void kernel_launch(void* const* d_in, const int* in_sizes, int n_in,
                              void* d_out, int out_size, void* d_ws, size_t ws_size,
                              hipStream_t stream) {
  const float* hs  = (const float*)d_in[0];
  const int*   pos = (const int*)d_in[1];
  const float* ct  = (const float*)d_in[2];
  const float* st  = (const float*)d_in[3];
  const float* Wq  = (const float*)d_in[4];
  const float* Wk  = (const float*)d_in[5];
  const float* Wv  = (const float*)d_in[6];
  const float* Wo  = (const float*)d_in[7];
  float* out = (float*)d_out;

  char* w = (char*)d_ws;
  u16* Xb    = (u16*)(w);                       // [4096][4096]
  u16* WqkvT = (u16*)(w + 33554432ull);         // [6144][4096]
  u16* WoT   = (u16*)(w + 83886080ull);         // [4096][4096]
  u16* Qb    = (u16*)(w + 117440512ull);        // [2][32][2048][128]
  u16* Kb    = (u16*)(w + 150994944ull);        // [2][8][2048][128]
  u16* Vb    = (u16*)(w + 159383552ull);        // [2][8][128][2048]
  u16* Attb  = (u16*)(w + 167772160ull);        // [4096][4096]

  k_convx<<<16384, 256, 0, stream>>>(hs, Xb, 4194304);
  k_convqkv<<<dim3(64, 96), 256, 0, stream>>>(Wq, Wk, Wv, WqkvT);
  k_convT<<<dim3(64, 64), 256, 0, stream>>>(Wo, WoT, 4096, 4096);
  k_gqkv<<<dim3(32, 16), 512, 0, stream>>>(Xb, WqkvT, Qb, Kb, Vb);
  k_rope2<<<40960, 256, 0, stream>>>(Qb, Kb, pos, ct, st);
  k_attn<<<1024, 256, 0, stream>>>(Qb, Kb, Vb, Attb);
  k_gemm_out<<<dim3(16, 16), 512, 0, stream>>>(Attb, WoT, out, 4096, 4096, 4096);
}

// Round 15
// 601.828 us; speedup vs baseline: 1.0260x; 1.0260x over previous
//
#include <hip/hip_runtime.h>
#include <stdint.h>

typedef unsigned short u16;
typedef __bf16 bf16x8 __attribute__((ext_vector_type(8)));
typedef unsigned short u16x8 __attribute__((ext_vector_type(8)));
typedef unsigned short u16x4 __attribute__((ext_vector_type(4)));
typedef float f32x4 __attribute__((ext_vector_type(4)));

#define B_ 2
#define S_ 2048
#define HID_ 4096
#define NH_ 32
#define NKV_ 8
#define HD_ 128
#define NTOT_ 6144
#define SCALE_ 0.08838834764831845f

#define GLD16(gp, lp)                                                     \
  __builtin_amdgcn_global_load_lds(                                       \
      (__attribute__((address_space(1))) void*)(gp),                      \
      (__attribute__((address_space(3))) void*)(lp), 16, 0, 0)

#define BAR __builtin_amdgcn_s_barrier()
#define PRIO1 __builtin_amdgcn_s_setprio(1)
#define PRIO0 __builtin_amdgcn_s_setprio(0)
#define VM8 asm volatile("s_waitcnt vmcnt(8)" ::: "memory")
#define VM0 asm volatile("s_waitcnt vmcnt(0)" ::: "memory")

// ---------- bf16 helpers ----------
__device__ __forceinline__ u16 f2b(float f) {
  union { float f; uint32_t u; } v; v.f = f;
  uint32_t u = v.u;
  u = u + 0x7fffu + ((u >> 16) & 1u);
  return (u16)(u >> 16);
}
__device__ __forceinline__ float b2f(u16 s) {
  union { uint32_t u; float f; } v; v.u = ((uint32_t)s) << 16;
  return v.f;
}
__device__ __forceinline__ bf16x8 ldb8(const u16* p) {
  u16x8 u = *(const u16x8*)p;
  return __builtin_bit_cast(bf16x8, u);
}
__device__ __forceinline__ bf16x8 ldb8b(const char* p) {
  u16x8 u = *(const u16x8*)p;
  return __builtin_bit_cast(bf16x8, u);
}

// ---------- merged prep kernel: convx + convqkv + convT(Wo) in one launch ----------
// blocks [0,16384): hidden f32->bf16 (elementwise, 1024 f32/block)
// blocks [16384,22528): Wq|Wk|Wv transpose-convert -> WqkvT [6144][4096]
// blocks [22528,26624): Wo transpose-convert -> WoT [4096][4096]
__global__ __launch_bounds__(256) void k_prep(const float* __restrict__ hs,
                                              u16* __restrict__ Xb,
                                              const float* __restrict__ Wq,
                                              const float* __restrict__ Wk,
                                              const float* __restrict__ Wv,
                                              u16* __restrict__ WqkvT,
                                              const float* __restrict__ Wo,
                                              u16* __restrict__ WoT) {
  __shared__ u16 tile[64][65];
  int bid = blockIdx.x;
  int t = threadIdx.x;
  if (bid < 16384) {
    int i = bid * 256 + t;
    const float4 v = ((const float4*)hs)[i];
    u16x4 o = { f2b(v.x), f2b(v.y), f2b(v.z), f2b(v.w) };
    *(u16x4*)(Xb + (size_t)i * 4) = o;
    return;
  }
  const float* src;
  u16* dst;
  int N, ns, ng, k0;
  const int Kd = HID_;
  if (bid < 16384 + 6144) {
    int ti = bid - 16384;
    k0 = (ti & 63) * 64;
    ng = (ti >> 6) * 64;
    dst = WqkvT;
    if (ng < 4096)      { src = Wq; N = 4096; ns = ng; }
    else if (ng < 5120) { src = Wk; N = 1024; ns = ng - 4096; }
    else                { src = Wv; N = 1024; ns = ng - 5120; }
  } else {
    int ti = bid - 16384 - 6144;
    k0 = (ti & 63) * 64;
    ng = (ti >> 6) * 64;
    src = Wo; dst = WoT; N = 4096; ns = ng;
  }
  int rr = t >> 4;
  int cc = (t & 15) * 4;
#pragma unroll
  for (int p = 0; p < 4; ++p) {
    int r = p * 16 + rr;
    float4 v = *(const float4*)&src[(size_t)(k0 + r) * N + ns + cc];
    tile[cc + 0][r] = f2b(v.x);
    tile[cc + 1][r] = f2b(v.y);
    tile[cc + 2][r] = f2b(v.z);
    tile[cc + 3][r] = f2b(v.w);
  }
  __syncthreads();
#pragma unroll
  for (int p = 0; p < 4; ++p) {
    int n = p * 16 + rr;
    u16x4 o = { tile[n][cc], tile[n][cc + 1], tile[n][cc + 2], tile[n][cc + 3] };
    *(u16x4*)&dst[(size_t)(ng + n) * Kd + k0 + cc] = o;
  }
}

// ---------- out-proj GEMM: 256x256, BK=64, template-discipline 8-phase (R13) ----------
__global__ __launch_bounds__(512) void k_gemm_out(const u16* __restrict__ A,
                                                  const u16* __restrict__ Bt,
                                                  float* __restrict__ Cf,
                                                  int M, int N, int Kd) {
  __shared__ __align__(16) char smem[131072];
  const int NT = Kd >> 6;

  int nwg = gridDim.x * gridDim.y;
  int orig = blockIdx.y * gridDim.x + blockIdx.x;
  int cpx = nwg >> 3;
  int swz = (orig & 7) * cpx + (orig >> 3);
  int bx = swz % gridDim.x, by = swz / gridDim.x;
  int m0 = by * 256, n0 = bx * 256;

  int t = threadIdx.x, lane = t & 63, wave = t >> 6;
  int wr = wave >> 2, wc = wave & 3;
  int lg = lane >> 4, l16 = lane & 15;
  int loff = l16 * 64 + ((lg ^ ((l16 >> 1) & 3)) << 4);
  int srow = lane >> 2, schk = (lane & 3) ^ ((lane >> 3) & 3);

  const u16* Asrc = A  + (size_t)(m0 + wave * 32 + srow) * Kd + schk * 8;
  const u16* Bsrc = Bt + (size_t)(n0 + wave * 32 + srow) * Kd + schk * 8;

  f32x4 acc[8][4] = {};

#define OST_A(tile, kc, BB) do {                                              \
    char* d_ = smem + (BB) + ((kc) << 14) + (wave << 11);                     \
    const u16* s_ = Asrc + (size_t)(tile) * 64 + (kc) * 32;                   \
    GLD16(s_, d_); GLD16(s_ + (size_t)16 * Kd, d_ + 1024); } while (0)
#define OST_B(tile, kc, BB) do {                                              \
    char* d_ = smem + (BB) + 32768 + ((kc) << 14) + (wave << 11);             \
    const u16* s_ = Bsrc + (size_t)(tile) * 64 + (kc) * 32;                   \
    GLD16(s_, d_); GLD16(s_ + (size_t)16 * Kd, d_ + 1024); } while (0)
#define OLDB(BB, kc) do { _Pragma("unroll")                                   \
    for (int j = 0; j < 4; ++j)                                               \
      bfr[j] = ldb8b(smem + (BB) + 32768 + ((kc) << 14) + ((wc * 4 + j) << 10) + loff); } while (0)
#define OLDA(BB, kc, mh) do { _Pragma("unroll")                               \
    for (int i = 0; i < 4; ++i)                                               \
      af[i] = ldb8b(smem + (BB) + ((kc) << 14) + ((wr * 8 + (mh) * 4 + i) << 10) + loff); } while (0)
#define OMFMA(mh) do { _Pragma("unroll")                                      \
    for (int i = 0; i < 4; ++i) { _Pragma("unroll")                           \
      for (int j = 0; j < 4; ++j)                                             \
        acc[(mh) * 4 + i][j] = __builtin_amdgcn_mfma_f32_16x16x32_bf16(af[i], bfr[j], acc[(mh) * 4 + i][j], 0, 0, 0); } } while (0)

  OST_A(0, 0, 0); OST_B(0, 0, 0); OST_A(0, 1, 0); OST_B(0, 1, 0);
  OST_A(1, 0, 65536); OST_B(1, 0, 65536);
  VM8; BAR;

  for (int it = 0; it < (NT >> 1); ++it) {
    int a = it << 1;
    bool pf = (a + 2 < NT);
    bf16x8 bfr[4], af[4];
    // P1
    OLDB(0, 0); OLDA(0, 0, 0); OST_A(a + 1, 1, 65536);
    BAR; PRIO1; OMFMA(0); PRIO0; BAR;
    // P2
    OLDA(0, 0, 1); OST_B(a + 1, 1, 65536);
    BAR; PRIO1; OMFMA(1); PRIO0; if (pf) { VM8; } else { VM0; } BAR;
    // P3
    OLDB(0, 1); OLDA(0, 1, 0); if (pf) OST_A(a + 2, 0, 0);
    BAR; PRIO1; OMFMA(0); PRIO0; BAR;
    // P4
    OLDA(0, 1, 1); if (pf) OST_B(a + 2, 0, 0);
    BAR; PRIO1; OMFMA(1); PRIO0; if (pf) { VM8; } else { VM0; } BAR;
    // P5
    OLDB(65536, 0); OLDA(65536, 0, 0); if (pf) OST_A(a + 2, 1, 0);
    BAR; PRIO1; OMFMA(0); PRIO0; BAR;
    // P6
    OLDA(65536, 0, 1); if (pf) OST_B(a + 2, 1, 0);
    BAR; PRIO1; OMFMA(1); PRIO0; if (pf) { VM8; } else { VM0; } BAR;
    // P7
    OLDB(65536, 1); OLDA(65536, 1, 0); if (pf) OST_A(a + 3, 0, 65536);
    BAR; PRIO1; OMFMA(0); PRIO0; BAR;
    // P8
    OLDA(65536, 1, 1); if (pf) OST_B(a + 3, 0, 65536);
    BAR; PRIO1; OMFMA(1); PRIO0; if (pf) { VM8; } else { VM0; } BAR;
  }
#undef OST_A
#undef OST_B
#undef OLDB
#undef OLDA
#undef OMFMA

#pragma unroll
  for (int i = 0; i < 8; ++i)
#pragma unroll
    for (int j = 0; j < 4; ++j)
#pragma unroll
      for (int r = 0; r < 4; ++r) {
        int m = m0 + wr * 128 + i * 16 + lg * 4 + r;
        int n = n0 + wc * 64 + j * 16 + l16;
        Cf[(size_t)m * N + n] = acc[i][j][r];
      }
}

// ---------- QKV GEMM: 256x192, BK=64, template-discipline 8-phase (R13) ----------
__global__ __launch_bounds__(512) void k_gqkv(const u16* __restrict__ A,
                                              const u16* __restrict__ Bt,
                                              u16* __restrict__ Qb,
                                              u16* __restrict__ Kb,
                                              u16* __restrict__ Vb) {
  __shared__ __align__(16) char smem[114688];
  const int Kd = HID_;
  const int NT = Kd >> 6;

  // grid 32x16 = 512, cpx = 64
  int orig = blockIdx.y * 32 + blockIdx.x;
  int swz = (orig & 7) * 64 + (orig >> 3);
  int bx = swz & 31, by = swz >> 5;
  int m0 = by * 256, n0 = bx * 192;

  int t = threadIdx.x, lane = t & 63, wave = t >> 6;
  int wr = wave >> 2, wc = wave & 3;
  int lg = lane >> 4, l16 = lane & 15;
  int loff = l16 * 64 + ((lg ^ ((l16 >> 1) & 3)) << 4);
  int srow = lane >> 2, schk = (lane & 3) ^ ((lane >> 3) & 3);

  const u16* Asrc = A + (size_t)(m0 + wave * 32 + srow) * Kd + schk * 8;
  const u16* sB0 = Bt + (size_t)(n0 + wave * 16 + srow) * Kd + schk * 8;
  const u16* sB1 = Bt + (size_t)(n0 + 128 + (wave & 3) * 16 + srow) * Kd + schk * 8;
  int bdst2 = (8 + (wave & 3)) << 10;

  f32x4 acc[8][3] = {};

#define QST_A(tile, kc, BB) do {                                              \
    char* d_ = smem + (BB) + ((kc) << 14) + (wave << 11);                     \
    const u16* s_ = Asrc + (size_t)(tile) * 64 + (kc) * 32;                   \
    GLD16(s_, d_); GLD16(s_ + (size_t)16 * Kd, d_ + 1024); } while (0)
#define QST_B(tile, kc, BB) do {                                              \
    char* db_ = smem + (BB) + 32768 + (kc) * 12288;                           \
    GLD16(sB0 + (size_t)(tile) * 64 + (kc) * 32, db_ + (wave << 10));         \
    GLD16(sB1 + (size_t)(tile) * 64 + (kc) * 32, db_ + bdst2); } while (0)
#define QLDB(BB, kc) do { _Pragma("unroll")                                   \
    for (int j = 0; j < 3; ++j)                                               \
      bfr[j] = ldb8b(smem + (BB) + 32768 + (kc) * 12288 + ((wc * 3 + j) << 10) + loff); } while (0)
#define QLDA(BB, kc, mh) do { _Pragma("unroll")                               \
    for (int i = 0; i < 4; ++i)                                               \
      af[i] = ldb8b(smem + (BB) + ((kc) << 14) + ((wr * 8 + (mh) * 4 + i) << 10) + loff); } while (0)
#define QMFMA(mh) do { _Pragma("unroll")                                      \
    for (int i = 0; i < 4; ++i) { _Pragma("unroll")                           \
      for (int j = 0; j < 3; ++j)                                             \
        acc[(mh) * 4 + i][j] = __builtin_amdgcn_mfma_f32_16x16x32_bf16(af[i], bfr[j], acc[(mh) * 4 + i][j], 0, 0, 0); } } while (0)

  QST_A(0, 0, 0); QST_B(0, 0, 0); QST_A(0, 1, 0); QST_B(0, 1, 0);
  QST_A(1, 0, 57344); QST_B(1, 0, 57344);
  VM8; BAR;

  for (int it = 0; it < (NT >> 1); ++it) {
    int a = it << 1;
    bool pf = (a + 2 < NT);
    bf16x8 bfr[3], af[4];
    // P1
    QLDB(0, 0); QLDA(0, 0, 0); QST_A(a + 1, 1, 57344);
    BAR; PRIO1; QMFMA(0); PRIO0; BAR;
    // P2
    QLDA(0, 0, 1); QST_B(a + 1, 1, 57344);
    BAR; PRIO1; QMFMA(1); PRIO0; if (pf) { VM8; } else { VM0; } BAR;
    // P3
    QLDB(0, 1); QLDA(0, 1, 0); if (pf) QST_A(a + 2, 0, 0);
    BAR; PRIO1; QMFMA(0); PRIO0; BAR;
    // P4
    QLDA(0, 1, 1); if (pf) QST_B(a + 2, 0, 0);
    BAR; PRIO1; QMFMA(1); PRIO0; if (pf) { VM8; } else { VM0; } BAR;
    // P5
    QLDB(57344, 0); QLDA(57344, 0, 0); if (pf) QST_A(a + 2, 1, 0);
    BAR; PRIO1; QMFMA(0); PRIO0; BAR;
    // P6
    QLDA(57344, 0, 1); if (pf) QST_B(a + 2, 1, 0);
    BAR; PRIO1; QMFMA(1); PRIO0; if (pf) { VM8; } else { VM0; } BAR;
    // P7
    QLDB(57344, 1); QLDA(57344, 1, 0); if (pf) QST_A(a + 3, 0, 57344);
    BAR; PRIO1; QMFMA(0); PRIO0; BAR;
    // P8
    QLDA(57344, 1, 1); if (pf) QST_B(a + 3, 0, 57344);
    BAR; PRIO1; QMFMA(1); PRIO0; if (pf) { VM8; } BAR;
  }
#undef QST_A
#undef QST_B
#undef QLDB
#undef QLDA
#undef QMFMA

  // epilogue: per-element head/d (192-wide N slice crosses head boundaries)
#pragma unroll
  for (int i = 0; i < 8; ++i)
#pragma unroll
    for (int j = 0; j < 3; ++j)
#pragma unroll
      for (int r = 0; r < 4; ++r) {
        int m = m0 + wr * 128 + i * 16 + lg * 4 + r;
        int n = n0 + wc * 48 + j * 16 + l16;
        int head = n >> 7, d = n & 127;
        int b = m >> 11, s = m & (S_ - 1);
        u16 val = f2b(acc[i][j][r]);
        if (head < NH_) {
          Qb[(((size_t)b * NH_ + head) * S_ + s) * HD_ + d] = val;
        } else if (head < NH_ + NKV_) {
          Kb[(((size_t)b * NKV_ + (head - NH_)) * S_ + s) * HD_ + d] = val;
        } else {
          Vb[(((size_t)b * NKV_ + (head - NH_ - NKV_)) * HD_ + d) * S_ + s] = val;
        }
      }
}

// ---------- kernel 4: merged RoPE (Q rows then K rows), one launch ----------
__global__ __launch_bounds__(256) void k_rope2(u16* __restrict__ Qb, u16* __restrict__ Kb,
                                               const int* __restrict__ pos,
                                               const float* __restrict__ ct,
                                               const float* __restrict__ st) {
  int wave = threadIdx.x >> 6, lane = threadIdx.x & 63;
  int row = blockIdx.x * 4 + wave;
  u16* buf;
  int H;
  if (row < B_ * NH_ * S_) { buf = Qb; H = NH_; }
  else { buf = Kb; H = NKV_; row -= B_ * NH_ * S_; }
  int s = row & (S_ - 1);
  int b = row / (H * S_);
  int p = pos[b * S_ + s];
  size_t base = (size_t)row * HD_;
  float x1 = b2f(buf[base + lane]);
  float x2 = b2f(buf[base + 64 + lane]);
  float c  = ct[(size_t)p * HD_ + lane];
  float sn = st[(size_t)p * HD_ + lane];
  buf[base + lane]      = f2b(x1 * c - x2 * sn);
  buf[base + 64 + lane] = f2b(x2 * c + x1 * sn);
}

// ---------- kernel 5: causal GQA flash attention (unchanged) ----------
__global__ __launch_bounds__(256, 4) void k_attn(const u16* __restrict__ Q,
                                                 const u16* __restrict__ K,
                                                 const u16* __restrict__ Vt,
                                                 u16* __restrict__ Ob) {
  __shared__ __align__(16) char smem[40960];
  const int VS_OFF = 16384, PS_OFF = 32768;

  int bid = blockIdx.x;
  int pid = bid & 15;
  int h   = (bid >> 4) & 31;
  int b   = bid >> 9;
  int kvh = h >> 2;
  int tid = threadIdx.x;
  int wave = tid >> 6, lane = tid & 63;
  int lg = lane >> 4, l16 = lane & 15;
  int lsw = (l16 & 7) << 4;

  const u16* Qp = Q  + (((size_t)b * NH_  + h)   * S_) * HD_;
  const u16* Kp = K  + (((size_t)b * NKV_ + kvh) * S_) * HD_;
  const u16* Vp = Vt + (((size_t)b * NKV_ + kvh) * HD_) * S_;

  for (int pass = 0; pass < 2; ++pass) {
    int qt = pass ? (31 - pid) : pid;
    int q0 = qt * 64 + wave * 16;
    int qg = q0 + l16;

    bf16x8 qf[4];
#pragma unroll
    for (int c = 0; c < 4; ++c)
      qf[c] = ldb8(&Qp[(size_t)qg * HD_ + c * 32 + lg * 8]);

    f32x4 oacc[8] = {};
    float mrun = -1e30f, lrun = 0.f;

    int nt = qt + 1;
    for (int tI = 0; tI < nt; ++tI) {
      int kb = tI * 64;
      __syncthreads();
#pragma unroll
      for (int i = 0; i < 4; ++i) {
        int ci = i * 256 + tid;
        int r = ci >> 4, ch = ci & 15;
        u16x8 v = *(const u16x8*)&Kp[(size_t)(kb + r) * HD_ + ch * 8];
        *(u16x8*)(smem + r * 256 + ((ch * 16) ^ ((r & 7) << 4))) = v;
      }
#pragma unroll
      for (int i = 0; i < 4; ++i) {
        int ci = i * 256 + tid;
        int r = ci >> 3, ch = ci & 7;
        u16x8 v = *(const u16x8*)&Vp[(size_t)r * S_ + kb + ch * 8];
        *(u16x8*)(smem + VS_OFF + r * 128 + ((ch * 16) ^ ((r & 7) << 4))) = v;
      }
      __syncthreads();

      f32x4 sc[4] = {};
#pragma unroll
      for (int c = 0; c < 4; ++c) {
#pragma unroll
        for (int n = 0; n < 4; ++n) {
          bf16x8 kf = ldb8b(smem + (n * 16 + l16) * 256 + ((c * 64 + lg * 16) ^ lsw));
          sc[n] = __builtin_amdgcn_mfma_f32_16x16x32_bf16(kf, qf[c], sc[n], 0, 0, 0);
        }
      }

      bool diag = (tI == qt);
      float mx = -1e30f;
#pragma unroll
      for (int n = 0; n < 4; ++n)
#pragma unroll
        for (int r = 0; r < 4; ++r) {
          float v = sc[n][r];
          int key = kb + n * 16 + lg * 4 + r;
          if (diag && key > qg) v = -1e30f;
          sc[n][r] = v;
          mx = fmaxf(mx, v);
        }
      mx = fmaxf(mx, __shfl_xor(mx, 16));
      mx = fmaxf(mx, __shfl_xor(mx, 32));
      float mnew = fmaxf(mrun, mx * SCALE_);
      float alpha = __expf(mrun - mnew);
      float ps = 0.f;
#pragma unroll
      for (int n = 0; n < 4; ++n) {
        u16x4 pk;
#pragma unroll
        for (int r = 0; r < 4; ++r) {
          float p = __expf(fmaf(sc[n][r], SCALE_, -mnew));
          ps += p;
          pk[r] = f2b(p);
        }
        *(u16x4*)(smem + PS_OFF + wave * 2048 + l16 * 128 + ((n * 32 + lg * 8) ^ lsw)) = pk;
      }
      ps += __shfl_xor(ps, 16);
      ps += __shfl_xor(ps, 32);
      lrun = lrun * alpha + ps;
      mrun = mnew;

      float ar[4];
#pragma unroll
      for (int r = 0; r < 4; ++r) ar[r] = __shfl(alpha, lg * 4 + r);
#pragma unroll
      for (int ns = 0; ns < 8; ++ns)
#pragma unroll
        for (int r = 0; r < 4; ++r) oacc[ns][r] *= ar[r];

#pragma unroll
      for (int ck = 0; ck < 2; ++ck) {
        bf16x8 pa = ldb8b(smem + PS_OFF + wave * 2048 + l16 * 128 + ((ck * 64 + lg * 16) ^ lsw));
#pragma unroll
        for (int ns = 0; ns < 8; ++ns) {
          bf16x8 vf = ldb8b(smem + VS_OFF + (ns * 16 + l16) * 128 + ((ck * 64 + lg * 16) ^ lsw));
          oacc[ns] = __builtin_amdgcn_mfma_f32_16x16x32_bf16(pa, vf, oacc[ns], 0, 0, 0);
        }
      }
    }

    float lr[4];
#pragma unroll
    for (int r = 0; r < 4; ++r) lr[r] = 1.0f / __shfl(lrun, lg * 4 + r);
#pragma unroll
    for (int ns = 0; ns < 8; ++ns)
#pragma unroll
      for (int r = 0; r < 4; ++r) {
        int q = q0 + lg * 4 + r;
        Ob[((size_t)(b * S_) + q) * (NH_ * HD_) + h * HD_ + ns * 16 + l16] =
            f2b(oacc[ns][r] * lr[r]);
      }
  }
}

// ---------- launch ----------
extern "C" void kernel_launch(void* const* d_in, const int* in_sizes, int n_in,
                              void* d_out, int out_size, void* d_ws, size_t ws_size,
                              hipStream_t stream) {
  const float* hs  = (const float*)d_in[0];
  const int*   pos = (const int*)d_in[1];
  const float* ct  = (const float*)d_in[2];
  const float* st  = (const float*)d_in[3];
  const float* Wq  = (const float*)d_in[4];
  const float* Wk  = (const float*)d_in[5];
  const float* Wv  = (const float*)d_in[6];
  const float* Wo  = (const float*)d_in[7];
  float* out = (float*)d_out;

  char* w = (char*)d_ws;
  u16* Xb    = (u16*)(w);                       // [4096][4096]
  u16* WqkvT = (u16*)(w + 33554432ull);         // [6144][4096]
  u16* WoT   = (u16*)(w + 83886080ull);         // [4096][4096]
  u16* Qb    = (u16*)(w + 117440512ull);        // [2][32][2048][128]
  u16* Kb    = (u16*)(w + 150994944ull);        // [2][8][2048][128]
  u16* Vb    = (u16*)(w + 159383552ull);        // [2][8][128][2048]
  u16* Attb  = (u16*)(w + 167772160ull);        // [4096][4096]

  k_prep<<<26624, 256, 0, stream>>>(hs, Xb, Wq, Wk, Wv, WqkvT, Wo, WoT);
  k_gqkv<<<dim3(32, 16), 512, 0, stream>>>(Xb, WqkvT, Qb, Kb, Vb);
  k_rope2<<<40960, 256, 0, stream>>>(Qb, Kb, pos, ct, st);
  k_attn<<<1024, 256, 0, stream>>>(Qb, Kb, Vb, Attb);
  k_gemm_out<<<dim3(16, 16), 512, 0, stream>>>(Attb, WoT, out, 4096, 4096, 4096);
}

// Round 16
// 600.353 us; speedup vs baseline: 1.0286x; 1.0025x over previous
//
#include <hip/hip_runtime.h>
#include <stdint.h>

typedef unsigned short u16;
typedef __bf16 bf16x8 __attribute__((ext_vector_type(8)));
typedef unsigned short u16x8 __attribute__((ext_vector_type(8)));
typedef unsigned short u16x4 __attribute__((ext_vector_type(4)));
typedef float f32x4 __attribute__((ext_vector_type(4)));

#define B_ 2
#define S_ 2048
#define HID_ 4096
#define NH_ 32
#define NKV_ 8
#define HD_ 128
#define NTOT_ 6144
#define SCALE_ 0.08838834764831845f

#define GLD16(gp, lp)                                                     \
  __builtin_amdgcn_global_load_lds(                                       \
      (__attribute__((address_space(1))) void*)(gp),                      \
      (__attribute__((address_space(3))) void*)(lp), 16, 0, 0)

#define BAR __builtin_amdgcn_s_barrier()
#define PRIO1 __builtin_amdgcn_s_setprio(1)
#define PRIO0 __builtin_amdgcn_s_setprio(0)
#define VM8 asm volatile("s_waitcnt vmcnt(8)" ::: "memory")
#define VM0 asm volatile("s_waitcnt vmcnt(0)" ::: "memory")

// ---------- bf16 helpers ----------
__device__ __forceinline__ u16 f2b(float f) {
  union { float f; uint32_t u; } v; v.f = f;
  uint32_t u = v.u;
  u = u + 0x7fffu + ((u >> 16) & 1u);
  return (u16)(u >> 16);
}
__device__ __forceinline__ float b2f(u16 s) {
  union { uint32_t u; float f; } v; v.u = ((uint32_t)s) << 16;
  return v.f;
}
__device__ __forceinline__ bf16x8 ldb8(const u16* p) {
  u16x8 u = *(const u16x8*)p;
  return __builtin_bit_cast(bf16x8, u);
}
__device__ __forceinline__ bf16x8 ldb8b(const char* p) {
  u16x8 u = *(const u16x8*)p;
  return __builtin_bit_cast(bf16x8, u);
}

// ---------- merged prep kernel: convx + convqkv + convT(Wo) in one launch ----------
__global__ __launch_bounds__(256) void k_prep(const float* __restrict__ hs,
                                              u16* __restrict__ Xb,
                                              const float* __restrict__ Wq,
                                              const float* __restrict__ Wk,
                                              const float* __restrict__ Wv,
                                              u16* __restrict__ WqkvT,
                                              const float* __restrict__ Wo,
                                              u16* __restrict__ WoT) {
  __shared__ u16 tile[64][65];
  int bid = blockIdx.x;
  int t = threadIdx.x;
  if (bid < 16384) {
    int i = bid * 256 + t;
    const float4 v = ((const float4*)hs)[i];
    u16x4 o = { f2b(v.x), f2b(v.y), f2b(v.z), f2b(v.w) };
    *(u16x4*)(Xb + (size_t)i * 4) = o;
    return;
  }
  const float* src;
  u16* dst;
  int N, ns, ng, k0;
  const int Kd = HID_;
  if (bid < 16384 + 6144) {
    int ti = bid - 16384;
    k0 = (ti & 63) * 64;
    ng = (ti >> 6) * 64;
    dst = WqkvT;
    if (ng < 4096)      { src = Wq; N = 4096; ns = ng; }
    else if (ng < 5120) { src = Wk; N = 1024; ns = ng - 4096; }
    else                { src = Wv; N = 1024; ns = ng - 5120; }
  } else {
    int ti = bid - 16384 - 6144;
    k0 = (ti & 63) * 64;
    ng = (ti >> 6) * 64;
    src = Wo; dst = WoT; N = 4096; ns = ng;
  }
  int rr = t >> 4;
  int cc = (t & 15) * 4;
#pragma unroll
  for (int p = 0; p < 4; ++p) {
    int r = p * 16 + rr;
    float4 v = *(const float4*)&src[(size_t)(k0 + r) * N + ns + cc];
    tile[cc + 0][r] = f2b(v.x);
    tile[cc + 1][r] = f2b(v.y);
    tile[cc + 2][r] = f2b(v.z);
    tile[cc + 3][r] = f2b(v.w);
  }
  __syncthreads();
#pragma unroll
  for (int p = 0; p < 4; ++p) {
    int n = p * 16 + rr;
    u16x4 o = { tile[n][cc], tile[n][cc + 1], tile[n][cc + 2], tile[n][cc + 3] };
    *(u16x4*)&dst[(size_t)(ng + n) * Kd + k0 + cc] = o;
  }
}

// ---------- out-proj GEMM: 256x256, BK=64, template-discipline 8-phase (R13) ----------
__global__ __launch_bounds__(512) void k_gemm_out(const u16* __restrict__ A,
                                                  const u16* __restrict__ Bt,
                                                  float* __restrict__ Cf,
                                                  int M, int N, int Kd) {
  __shared__ __align__(16) char smem[131072];
  const int NT = Kd >> 6;

  int nwg = gridDim.x * gridDim.y;
  int orig = blockIdx.y * gridDim.x + blockIdx.x;
  int cpx = nwg >> 3;
  int swz = (orig & 7) * cpx + (orig >> 3);
  int bx = swz % gridDim.x, by = swz / gridDim.x;
  int m0 = by * 256, n0 = bx * 256;

  int t = threadIdx.x, lane = t & 63, wave = t >> 6;
  int wr = wave >> 2, wc = wave & 3;
  int lg = lane >> 4, l16 = lane & 15;
  int loff = l16 * 64 + ((lg ^ ((l16 >> 1) & 3)) << 4);
  int srow = lane >> 2, schk = (lane & 3) ^ ((lane >> 3) & 3);

  const u16* Asrc = A  + (size_t)(m0 + wave * 32 + srow) * Kd + schk * 8;
  const u16* Bsrc = Bt + (size_t)(n0 + wave * 32 + srow) * Kd + schk * 8;

  f32x4 acc[8][4] = {};

#define OST_A(tile, kc, BB) do {                                              \
    char* d_ = smem + (BB) + ((kc) << 14) + (wave << 11);                     \
    const u16* s_ = Asrc + (size_t)(tile) * 64 + (kc) * 32;                   \
    GLD16(s_, d_); GLD16(s_ + (size_t)16 * Kd, d_ + 1024); } while (0)
#define OST_B(tile, kc, BB) do {                                              \
    char* d_ = smem + (BB) + 32768 + ((kc) << 14) + (wave << 11);             \
    const u16* s_ = Bsrc + (size_t)(tile) * 64 + (kc) * 32;                   \
    GLD16(s_, d_); GLD16(s_ + (size_t)16 * Kd, d_ + 1024); } while (0)
#define OLDB(BB, kc) do { _Pragma("unroll")                                   \
    for (int j = 0; j < 4; ++j)                                               \
      bfr[j] = ldb8b(smem + (BB) + 32768 + ((kc) << 14) + ((wc * 4 + j) << 10) + loff); } while (0)
#define OLDA(BB, kc, mh) do { _Pragma("unroll")                               \
    for (int i = 0; i < 4; ++i)                                               \
      af[i] = ldb8b(smem + (BB) + ((kc) << 14) + ((wr * 8 + (mh) * 4 + i) << 10) + loff); } while (0)
#define OMFMA(mh) do { _Pragma("unroll")                                      \
    for (int i = 0; i < 4; ++i) { _Pragma("unroll")                           \
      for (int j = 0; j < 4; ++j)                                             \
        acc[(mh) * 4 + i][j] = __builtin_amdgcn_mfma_f32_16x16x32_bf16(af[i], bfr[j], acc[(mh) * 4 + i][j], 0, 0, 0); } } while (0)

  OST_A(0, 0, 0); OST_B(0, 0, 0); OST_A(0, 1, 0); OST_B(0, 1, 0);
  OST_A(1, 0, 65536); OST_B(1, 0, 65536);
  VM8; BAR;

  for (int it = 0; it < (NT >> 1); ++it) {
    int a = it << 1;
    bool pf = (a + 2 < NT);
    bf16x8 bfr[4], af[4];
    // P1
    OLDB(0, 0); OLDA(0, 0, 0); OST_A(a + 1, 1, 65536);
    BAR; PRIO1; OMFMA(0); PRIO0; BAR;
    // P2
    OLDA(0, 0, 1); OST_B(a + 1, 1, 65536);
    BAR; PRIO1; OMFMA(1); PRIO0; if (pf) { VM8; } else { VM0; } BAR;
    // P3
    OLDB(0, 1); OLDA(0, 1, 0); if (pf) OST_A(a + 2, 0, 0);
    BAR; PRIO1; OMFMA(0); PRIO0; BAR;
    // P4
    OLDA(0, 1, 1); if (pf) OST_B(a + 2, 0, 0);
    BAR; PRIO1; OMFMA(1); PRIO0; if (pf) { VM8; } else { VM0; } BAR;
    // P5
    OLDB(65536, 0); OLDA(65536, 0, 0); if (pf) OST_A(a + 2, 1, 0);
    BAR; PRIO1; OMFMA(0); PRIO0; BAR;
    // P6
    OLDA(65536, 0, 1); if (pf) OST_B(a + 2, 1, 0);
    BAR; PRIO1; OMFMA(1); PRIO0; if (pf) { VM8; } else { VM0; } BAR;
    // P7
    OLDB(65536, 1); OLDA(65536, 1, 0); if (pf) OST_A(a + 3, 0, 65536);
    BAR; PRIO1; OMFMA(0); PRIO0; BAR;
    // P8
    OLDA(65536, 1, 1); if (pf) OST_B(a + 3, 0, 65536);
    BAR; PRIO1; OMFMA(1); PRIO0; if (pf) { VM8; } else { VM0; } BAR;
  }
#undef OST_A
#undef OST_B
#undef OLDB
#undef OLDA
#undef OMFMA

#pragma unroll
  for (int i = 0; i < 8; ++i)
#pragma unroll
    for (int j = 0; j < 4; ++j)
#pragma unroll
      for (int r = 0; r < 4; ++r) {
        int m = m0 + wr * 128 + i * 16 + lg * 4 + r;
        int n = n0 + wc * 64 + j * 16 + l16;
        Cf[(size_t)m * N + n] = acc[i][j][r];
      }
}

// ---------- QKV GEMM: 256x192, BK=64, template-discipline 8-phase (R13) ----------
__global__ __launch_bounds__(512) void k_gqkv(const u16* __restrict__ A,
                                              const u16* __restrict__ Bt,
                                              u16* __restrict__ Qb,
                                              u16* __restrict__ Kb,
                                              u16* __restrict__ Vb) {
  __shared__ __align__(16) char smem[114688];
  const int Kd = HID_;
  const int NT = Kd >> 6;

  // grid 32x16 = 512, cpx = 64
  int orig = blockIdx.y * 32 + blockIdx.x;
  int swz = (orig & 7) * 64 + (orig >> 3);
  int bx = swz & 31, by = swz >> 5;
  int m0 = by * 256, n0 = bx * 192;

  int t = threadIdx.x, lane = t & 63, wave = t >> 6;
  int wr = wave >> 2, wc = wave & 3;
  int lg = lane >> 4, l16 = lane & 15;
  int loff = l16 * 64 + ((lg ^ ((l16 >> 1) & 3)) << 4);
  int srow = lane >> 2, schk = (lane & 3) ^ ((lane >> 3) & 3);

  const u16* Asrc = A + (size_t)(m0 + wave * 32 + srow) * Kd + schk * 8;
  const u16* sB0 = Bt + (size_t)(n0 + wave * 16 + srow) * Kd + schk * 8;
  const u16* sB1 = Bt + (size_t)(n0 + 128 + (wave & 3) * 16 + srow) * Kd + schk * 8;
  int bdst2 = (8 + (wave & 3)) << 10;

  f32x4 acc[8][3] = {};

#define QST_A(tile, kc, BB) do {                                              \
    char* d_ = smem + (BB) + ((kc) << 14) + (wave << 11);                     \
    const u16* s_ = Asrc + (size_t)(tile) * 64 + (kc) * 32;                   \
    GLD16(s_, d_); GLD16(s_ + (size_t)16 * Kd, d_ + 1024); } while (0)
#define QST_B(tile, kc, BB) do {                                              \
    char* db_ = smem + (BB) + 32768 + (kc) * 12288;                           \
    GLD16(sB0 + (size_t)(tile) * 64 + (kc) * 32, db_ + (wave << 10));         \
    GLD16(sB1 + (size_t)(tile) * 64 + (kc) * 32, db_ + bdst2); } while (0)
#define QLDB(BB, kc) do { _Pragma("unroll")                                   \
    for (int j = 0; j < 3; ++j)                                               \
      bfr[j] = ldb8b(smem + (BB) + 32768 + (kc) * 12288 + ((wc * 3 + j) << 10) + loff); } while (0)
#define QLDA(BB, kc, mh) do { _Pragma("unroll")                               \
    for (int i = 0; i < 4; ++i)                                               \
      af[i] = ldb8b(smem + (BB) + ((kc) << 14) + ((wr * 8 + (mh) * 4 + i) << 10) + loff); } while (0)
#define QMFMA(mh) do { _Pragma("unroll")                                      \
    for (int i = 0; i < 4; ++i) { _Pragma("unroll")                           \
      for (int j = 0; j < 3; ++j)                                             \
        acc[(mh) * 4 + i][j] = __builtin_amdgcn_mfma_f32_16x16x32_bf16(af[i], bfr[j], acc[(mh) * 4 + i][j], 0, 0, 0); } } while (0)

  QST_A(0, 0, 0); QST_B(0, 0, 0); QST_A(0, 1, 0); QST_B(0, 1, 0);
  QST_A(1, 0, 57344); QST_B(1, 0, 57344);
  VM8; BAR;

  for (int it = 0; it < (NT >> 1); ++it) {
    int a = it << 1;
    bool pf = (a + 2 < NT);
    bf16x8 bfr[3], af[4];
    // P1
    QLDB(0, 0); QLDA(0, 0, 0); QST_A(a + 1, 1, 57344);
    BAR; PRIO1; QMFMA(0); PRIO0; BAR;
    // P2
    QLDA(0, 0, 1); QST_B(a + 1, 1, 57344);
    BAR; PRIO1; QMFMA(1); PRIO0; if (pf) { VM8; } else { VM0; } BAR;
    // P3
    QLDB(0, 1); QLDA(0, 1, 0); if (pf) QST_A(a + 2, 0, 0);
    BAR; PRIO1; QMFMA(0); PRIO0; BAR;
    // P4
    QLDA(0, 1, 1); if (pf) QST_B(a + 2, 0, 0);
    BAR; PRIO1; QMFMA(1); PRIO0; if (pf) { VM8; } else { VM0; } BAR;
    // P5
    QLDB(57344, 0); QLDA(57344, 0, 0); if (pf) QST_A(a + 2, 1, 0);
    BAR; PRIO1; QMFMA(0); PRIO0; BAR;
    // P6
    QLDA(57344, 0, 1); if (pf) QST_B(a + 2, 1, 0);
    BAR; PRIO1; QMFMA(1); PRIO0; if (pf) { VM8; } else { VM0; } BAR;
    // P7
    QLDB(57344, 1); QLDA(57344, 1, 0); if (pf) QST_A(a + 3, 0, 57344);
    BAR; PRIO1; QMFMA(0); PRIO0; BAR;
    // P8
    QLDA(57344, 1, 1); if (pf) QST_B(a + 3, 0, 57344);
    BAR; PRIO1; QMFMA(1); PRIO0; if (pf) { VM8; } BAR;
  }
#undef QST_A
#undef QST_B
#undef QLDB
#undef QLDA
#undef QMFMA

  // epilogue: per-element head/d (192-wide N slice crosses head boundaries)
#pragma unroll
  for (int i = 0; i < 8; ++i)
#pragma unroll
    for (int j = 0; j < 3; ++j)
#pragma unroll
      for (int r = 0; r < 4; ++r) {
        int m = m0 + wr * 128 + i * 16 + lg * 4 + r;
        int n = n0 + wc * 48 + j * 16 + l16;
        int head = n >> 7, d = n & 127;
        int b = m >> 11, s = m & (S_ - 1);
        u16 val = f2b(acc[i][j][r]);
        if (head < NH_) {
          Qb[(((size_t)b * NH_ + head) * S_ + s) * HD_ + d] = val;
        } else if (head < NH_ + NKV_) {
          Kb[(((size_t)b * NKV_ + (head - NH_)) * S_ + s) * HD_ + d] = val;
        } else {
          Vb[(((size_t)b * NKV_ + (head - NH_ - NKV_)) * HD_ + d) * S_ + s] = val;
        }
      }
}

// ---------- kernel 4: RoPE on K only (Q fused into attention) ----------
__global__ __launch_bounds__(256) void k_ropek(u16* __restrict__ Kb,
                                               const int* __restrict__ pos,
                                               const float* __restrict__ ct,
                                               const float* __restrict__ st) {
  int wave = threadIdx.x >> 6, lane = threadIdx.x & 63;
  int row = blockIdx.x * 4 + wave;   // 0 .. B*NKV*S-1
  int s = row & (S_ - 1);
  int b = row / (NKV_ * S_);
  int p = pos[b * S_ + s];
  size_t base = (size_t)row * HD_;
  float x1 = b2f(Kb[base + lane]);
  float x2 = b2f(Kb[base + 64 + lane]);
  float c  = ct[(size_t)p * HD_ + lane];
  float sn = st[(size_t)p * HD_ + lane];
  Kb[base + lane]      = f2b(x1 * c - x2 * sn);
  Kb[base + 64 + lane] = f2b(x2 * c + x1 * sn);
}

// ---------- kernel 5: causal GQA flash attention + fused Q-RoPE ----------
__global__ __launch_bounds__(256, 4) void k_attn(const u16* __restrict__ Q,
                                                 const u16* __restrict__ K,
                                                 const u16* __restrict__ Vt,
                                                 u16* __restrict__ Ob,
                                                 const int* __restrict__ pos,
                                                 const float* __restrict__ ct,
                                                 const float* __restrict__ st) {
  __shared__ __align__(16) char smem[40960];
  const int VS_OFF = 16384, PS_OFF = 32768;

  int bid = blockIdx.x;
  int pid = bid & 15;
  int h   = (bid >> 4) & 31;
  int b   = bid >> 9;
  int kvh = h >> 2;
  int tid = threadIdx.x;
  int wave = tid >> 6, lane = tid & 63;
  int lg = lane >> 4, l16 = lane & 15;
  int lsw = (l16 & 7) << 4;

  const u16* Qp = Q  + (((size_t)b * NH_  + h)   * S_) * HD_;
  const u16* Kp = K  + (((size_t)b * NKV_ + kvh) * S_) * HD_;
  const u16* Vp = Vt + (((size_t)b * NKV_ + kvh) * HD_) * S_;

  for (int pass = 0; pass < 2; ++pass) {
    int qt = pass ? (31 - pid) : pid;
    int q0 = qt * 64 + wave * 16;
    int qg = q0 + l16;

    // load Q fragments and apply RoPE in-register:
    // d = c*32 + lg*8 + e; pair partner d±64 lives at qf[c^2][e] (same thread)
    u16x8 qu[4];
#pragma unroll
    for (int c = 0; c < 4; ++c)
      qu[c] = *(const u16x8*)&Qp[(size_t)qg * HD_ + c * 32 + lg * 8];
    int prot = pos[b * S_ + qg];
    const float* cb = ct + (size_t)prot * HD_;
    const float* sb = st + (size_t)prot * HD_;
    bf16x8 qf[4];
#pragma unroll
    for (int c = 0; c < 4; ++c) {
      int d0 = c * 32 + lg * 8;
      u16x8 o;
#pragma unroll
      for (int e = 0; e < 8; ++e) {
        float x  = b2f(qu[c][e]);
        float xp = b2f(qu[c ^ 2][e]);
        float cc = cb[d0 + e];
        float ss = sb[d0 + e];
        float res = (c < 2) ? (x * cc - xp * ss) : fmaf(xp, ss, x * cc);
        o[e] = f2b(res);
      }
      qf[c] = __builtin_bit_cast(bf16x8, o);
    }

    f32x4 oacc[8] = {};
    float mrun = -1e30f, lrun = 0.f;

    int nt = qt + 1;
    for (int tI = 0; tI < nt; ++tI) {
      int kb = tI * 64;
      __syncthreads();
#pragma unroll
      for (int i = 0; i < 4; ++i) {
        int ci = i * 256 + tid;
        int r = ci >> 4, ch = ci & 15;
        u16x8 v = *(const u16x8*)&Kp[(size_t)(kb + r) * HD_ + ch * 8];
        *(u16x8*)(smem + r * 256 + ((ch * 16) ^ ((r & 7) << 4))) = v;
      }
#pragma unroll
      for (int i = 0; i < 4; ++i) {
        int ci = i * 256 + tid;
        int r = ci >> 3, ch = ci & 7;
        u16x8 v = *(const u16x8*)&Vp[(size_t)r * S_ + kb + ch * 8];
        *(u16x8*)(smem + VS_OFF + r * 128 + ((ch * 16) ^ ((r & 7) << 4))) = v;
      }
      __syncthreads();

      f32x4 sc[4] = {};
#pragma unroll
      for (int c = 0; c < 4; ++c) {
#pragma unroll
        for (int n = 0; n < 4; ++n) {
          bf16x8 kf = ldb8b(smem + (n * 16 + l16) * 256 + ((c * 64 + lg * 16) ^ lsw));
          sc[n] = __builtin_amdgcn_mfma_f32_16x16x32_bf16(kf, qf[c], sc[n], 0, 0, 0);
        }
      }

      bool diag = (tI == qt);
      float mx = -1e30f;
#pragma unroll
      for (int n = 0; n < 4; ++n)
#pragma unroll
        for (int r = 0; r < 4; ++r) {
          float v = sc[n][r];
          int key = kb + n * 16 + lg * 4 + r;
          if (diag && key > qg) v = -1e30f;
          sc[n][r] = v;
          mx = fmaxf(mx, v);
        }
      mx = fmaxf(mx, __shfl_xor(mx, 16));
      mx = fmaxf(mx, __shfl_xor(mx, 32));
      float mnew = fmaxf(mrun, mx * SCALE_);
      float alpha = __expf(mrun - mnew);
      float ps = 0.f;
#pragma unroll
      for (int n = 0; n < 4; ++n) {
        u16x4 pk;
#pragma unroll
        for (int r = 0; r < 4; ++r) {
          float p = __expf(fmaf(sc[n][r], SCALE_, -mnew));
          ps += p;
          pk[r] = f2b(p);
        }
        *(u16x4*)(smem + PS_OFF + wave * 2048 + l16 * 128 + ((n * 32 + lg * 8) ^ lsw)) = pk;
      }
      ps += __shfl_xor(ps, 16);
      ps += __shfl_xor(ps, 32);
      lrun = lrun * alpha + ps;
      mrun = mnew;

      float ar[4];
#pragma unroll
      for (int r = 0; r < 4; ++r) ar[r] = __shfl(alpha, lg * 4 + r);
#pragma unroll
      for (int ns = 0; ns < 8; ++ns)
#pragma unroll
        for (int r = 0; r < 4; ++r) oacc[ns][r] *= ar[r];

#pragma unroll
      for (int ck = 0; ck < 2; ++ck) {
        bf16x8 pa = ldb8b(smem + PS_OFF + wave * 2048 + l16 * 128 + ((ck * 64 + lg * 16) ^ lsw));
#pragma unroll
        for (int ns = 0; ns < 8; ++ns) {
          bf16x8 vf = ldb8b(smem + VS_OFF + (ns * 16 + l16) * 128 + ((ck * 64 + lg * 16) ^ lsw));
          oacc[ns] = __builtin_amdgcn_mfma_f32_16x16x32_bf16(pa, vf, oacc[ns], 0, 0, 0);
        }
      }
    }

    float lr[4];
#pragma unroll
    for (int r = 0; r < 4; ++r) lr[r] = 1.0f / __shfl(lrun, lg * 4 + r);
#pragma unroll
    for (int ns = 0; ns < 8; ++ns)
#pragma unroll
      for (int r = 0; r < 4; ++r) {
        int q = q0 + lg * 4 + r;
        Ob[((size_t)(b * S_) + q) * (NH_ * HD_) + h * HD_ + ns * 16 + l16] =
            f2b(oacc[ns][r] * lr[r]);
      }
  }
}

// ---------- launch ----------
extern "C" void kernel_launch(void* const* d_in, const int* in_sizes, int n_in,
                              void* d_out, int out_size, void* d_ws, size_t ws_size,
                              hipStream_t stream) {
  const float* hs  = (const float*)d_in[0];
  const int*   pos = (const int*)d_in[1];
  const float* ct  = (const float*)d_in[2];
  const float* st  = (const float*)d_in[3];
  const float* Wq  = (const float*)d_in[4];
  const float* Wk  = (const float*)d_in[5];
  const float* Wv  = (const float*)d_in[6];
  const float* Wo  = (const float*)d_in[7];
  float* out = (float*)d_out;

  char* w = (char*)d_ws;
  u16* Xb    = (u16*)(w);                       // [4096][4096]
  u16* WqkvT = (u16*)(w + 33554432ull);         // [6144][4096]
  u16* WoT   = (u16*)(w + 83886080ull);         // [4096][4096]
  u16* Qb    = (u16*)(w + 117440512ull);        // [2][32][2048][128]
  u16* Kb    = (u16*)(w + 150994944ull);        // [2][8][2048][128]
  u16* Vb    = (u16*)(w + 159383552ull);        // [2][8][128][2048]
  u16* Attb  = (u16*)(w + 167772160ull);        // [4096][4096]

  k_prep<<<26624, 256, 0, stream>>>(hs, Xb, Wq, Wk, Wv, WqkvT, Wo, WoT);
  k_gqkv<<<dim3(32, 16), 512, 0, stream>>>(Xb, WqkvT, Qb, Kb, Vb);
  k_ropek<<<8192, 256, 0, stream>>>(Kb, pos, ct, st);
  k_attn<<<1024, 256, 0, stream>>>(Qb, Kb, Vb, Attb, pos, ct, st);
  k_gemm_out<<<dim3(16, 16), 512, 0, stream>>>(Attb, WoT, out, 4096, 4096, 4096);
}

// Round 17
// 590.991 us; speedup vs baseline: 1.0449x; 1.0158x over previous
//
#include <hip/hip_runtime.h>
#include <stdint.h>

typedef unsigned short u16;
typedef __bf16 bf16x8 __attribute__((ext_vector_type(8)));
typedef unsigned short u16x8 __attribute__((ext_vector_type(8)));
typedef unsigned short u16x4 __attribute__((ext_vector_type(4)));
typedef float f32x4 __attribute__((ext_vector_type(4)));

#define B_ 2
#define S_ 2048
#define HID_ 4096
#define NH_ 32
#define NKV_ 8
#define HD_ 128
#define NTOT_ 6144
#define SCALE_ 0.08838834764831845f

#define GLD16(gp, lp)                                                     \
  __builtin_amdgcn_global_load_lds(                                       \
      (__attribute__((address_space(1))) void*)(gp),                      \
      (__attribute__((address_space(3))) void*)(lp), 16, 0, 0)

#define BAR __builtin_amdgcn_s_barrier()
#define PRIO1 __builtin_amdgcn_s_setprio(1)
#define PRIO0 __builtin_amdgcn_s_setprio(0)
#define VM8 asm volatile("s_waitcnt vmcnt(8)" ::: "memory")
#define VM0 asm volatile("s_waitcnt vmcnt(0)" ::: "memory")

// ---------- bf16 helpers ----------
__device__ __forceinline__ u16 f2b(float f) {
  union { float f; uint32_t u; } v; v.f = f;
  uint32_t u = v.u;
  u = u + 0x7fffu + ((u >> 16) & 1u);
  return (u16)(u >> 16);
}
__device__ __forceinline__ float b2f(u16 s) {
  union { uint32_t u; float f; } v; v.u = ((uint32_t)s) << 16;
  return v.f;
}
__device__ __forceinline__ bf16x8 ldb8(const u16* p) {
  u16x8 u = *(const u16x8*)p;
  return __builtin_bit_cast(bf16x8, u);
}
__device__ __forceinline__ bf16x8 ldb8b(const char* p) {
  u16x8 u = *(const u16x8*)p;
  return __builtin_bit_cast(bf16x8, u);
}

// ---------- merged prep kernel: convx + convqkv + convT(Wo) in one launch ----------
__global__ __launch_bounds__(256) void k_prep(const float* __restrict__ hs,
                                              u16* __restrict__ Xb,
                                              const float* __restrict__ Wq,
                                              const float* __restrict__ Wk,
                                              const float* __restrict__ Wv,
                                              u16* __restrict__ WqkvT,
                                              const float* __restrict__ Wo,
                                              u16* __restrict__ WoT) {
  __shared__ u16 tile[64][65];
  int bid = blockIdx.x;
  int t = threadIdx.x;
  if (bid < 16384) {
    int i = bid * 256 + t;
    const float4 v = ((const float4*)hs)[i];
    u16x4 o = { f2b(v.x), f2b(v.y), f2b(v.z), f2b(v.w) };
    *(u16x4*)(Xb + (size_t)i * 4) = o;
    return;
  }
  const float* src;
  u16* dst;
  int N, ns, ng, k0;
  const int Kd = HID_;
  if (bid < 16384 + 6144) {
    int ti = bid - 16384;
    k0 = (ti & 63) * 64;
    ng = (ti >> 6) * 64;
    dst = WqkvT;
    if (ng < 4096)      { src = Wq; N = 4096; ns = ng; }
    else if (ng < 5120) { src = Wk; N = 1024; ns = ng - 4096; }
    else                { src = Wv; N = 1024; ns = ng - 5120; }
  } else {
    int ti = bid - 16384 - 6144;
    k0 = (ti & 63) * 64;
    ng = (ti >> 6) * 64;
    src = Wo; dst = WoT; N = 4096; ns = ng;
  }
  int rr = t >> 4;
  int cc = (t & 15) * 4;
#pragma unroll
  for (int p = 0; p < 4; ++p) {
    int r = p * 16 + rr;
    float4 v = *(const float4*)&src[(size_t)(k0 + r) * N + ns + cc];
    tile[cc + 0][r] = f2b(v.x);
    tile[cc + 1][r] = f2b(v.y);
    tile[cc + 2][r] = f2b(v.z);
    tile[cc + 3][r] = f2b(v.w);
  }
  __syncthreads();
#pragma unroll
  for (int p = 0; p < 4; ++p) {
    int n = p * 16 + rr;
    u16x4 o = { tile[n][cc], tile[n][cc + 1], tile[n][cc + 2], tile[n][cc + 3] };
    *(u16x4*)&dst[(size_t)(ng + n) * Kd + k0 + cc] = o;
  }
}

// ---------- out-proj GEMM: 256x256, BK=64, 8-phase, single-barrier phases ----------
// Phase = reads; stage; PRIO1 MFMA PRIO0; [VM]; BAR. BAR1 removed (R17):
// MFMA<-reads is per-wave lgkm; WAR stage-vs-elder-reads separated by >=1
// closing BAR (drift <1 phase); RAW carried by unchanged VM8 cadence (queue
// 12->8, retires the 4 loads read two phases later; tails VM0/empty).
__global__ __launch_bounds__(512) void k_gemm_out(const u16* __restrict__ A,
                                                  const u16* __restrict__ Bt,
                                                  float* __restrict__ Cf,
                                                  int M, int N, int Kd) {
  __shared__ __align__(16) char smem[131072];
  const int NT = Kd >> 6;

  int nwg = gridDim.x * gridDim.y;
  int orig = blockIdx.y * gridDim.x + blockIdx.x;
  int cpx = nwg >> 3;
  int swz = (orig & 7) * cpx + (orig >> 3);
  int bx = swz % gridDim.x, by = swz / gridDim.x;
  int m0 = by * 256, n0 = bx * 256;

  int t = threadIdx.x, lane = t & 63, wave = t >> 6;
  int wr = wave >> 2, wc = wave & 3;
  int lg = lane >> 4, l16 = lane & 15;
  int loff = l16 * 64 + ((lg ^ ((l16 >> 1) & 3)) << 4);
  int srow = lane >> 2, schk = (lane & 3) ^ ((lane >> 3) & 3);

  const u16* Asrc = A  + (size_t)(m0 + wave * 32 + srow) * Kd + schk * 8;
  const u16* Bsrc = Bt + (size_t)(n0 + wave * 32 + srow) * Kd + schk * 8;

  f32x4 acc[8][4] = {};

#define OST_A(tile, kc, BB) do {                                              \
    char* d_ = smem + (BB) + ((kc) << 14) + (wave << 11);                     \
    const u16* s_ = Asrc + (size_t)(tile) * 64 + (kc) * 32;                   \
    GLD16(s_, d_); GLD16(s_ + (size_t)16 * Kd, d_ + 1024); } while (0)
#define OST_B(tile, kc, BB) do {                                              \
    char* d_ = smem + (BB) + 32768 + ((kc) << 14) + (wave << 11);             \
    const u16* s_ = Bsrc + (size_t)(tile) * 64 + (kc) * 32;                   \
    GLD16(s_, d_); GLD16(s_ + (size_t)16 * Kd, d_ + 1024); } while (0)
#define OLDB(BB, kc) do { _Pragma("unroll")                                   \
    for (int j = 0; j < 4; ++j)                                               \
      bfr[j] = ldb8b(smem + (BB) + 32768 + ((kc) << 14) + ((wc * 4 + j) << 10) + loff); } while (0)
#define OLDA(BB, kc, mh) do { _Pragma("unroll")                               \
    for (int i = 0; i < 4; ++i)                                               \
      af[i] = ldb8b(smem + (BB) + ((kc) << 14) + ((wr * 8 + (mh) * 4 + i) << 10) + loff); } while (0)
#define OMFMA(mh) do { _Pragma("unroll")                                      \
    for (int i = 0; i < 4; ++i) { _Pragma("unroll")                           \
      for (int j = 0; j < 4; ++j)                                             \
        acc[(mh) * 4 + i][j] = __builtin_amdgcn_mfma_f32_16x16x32_bf16(af[i], bfr[j], acc[(mh) * 4 + i][j], 0, 0, 0); } } while (0)

  OST_A(0, 0, 0); OST_B(0, 0, 0); OST_A(0, 1, 0); OST_B(0, 1, 0);
  OST_A(1, 0, 65536); OST_B(1, 0, 65536);
  VM8; BAR;

  for (int it = 0; it < (NT >> 1); ++it) {
    int a = it << 1;
    bool pf = (a + 2 < NT);
    bf16x8 bfr[4], af[4];
    // P1
    OLDB(0, 0); OLDA(0, 0, 0); OST_A(a + 1, 1, 65536);
    PRIO1; OMFMA(0); PRIO0; BAR;
    // P2
    OLDA(0, 0, 1); OST_B(a + 1, 1, 65536);
    PRIO1; OMFMA(1); PRIO0; if (pf) { VM8; } else { VM0; } BAR;
    // P3
    OLDB(0, 1); OLDA(0, 1, 0); if (pf) OST_A(a + 2, 0, 0);
    PRIO1; OMFMA(0); PRIO0; BAR;
    // P4
    OLDA(0, 1, 1); if (pf) OST_B(a + 2, 0, 0);
    PRIO1; OMFMA(1); PRIO0; if (pf) { VM8; } else { VM0; } BAR;
    // P5
    OLDB(65536, 0); OLDA(65536, 0, 0); if (pf) OST_A(a + 2, 1, 0);
    PRIO1; OMFMA(0); PRIO0; BAR;
    // P6
    OLDA(65536, 0, 1); if (pf) OST_B(a + 2, 1, 0);
    PRIO1; OMFMA(1); PRIO0; if (pf) { VM8; } else { VM0; } BAR;
    // P7
    OLDB(65536, 1); OLDA(65536, 1, 0); if (pf) OST_A(a + 3, 0, 65536);
    PRIO1; OMFMA(0); PRIO0; BAR;
    // P8
    OLDA(65536, 1, 1); if (pf) OST_B(a + 3, 0, 65536);
    PRIO1; OMFMA(1); PRIO0; if (pf) { VM8; } BAR;
  }
#undef OST_A
#undef OST_B
#undef OLDB
#undef OLDA
#undef OMFMA

#pragma unroll
  for (int i = 0; i < 8; ++i)
#pragma unroll
    for (int j = 0; j < 4; ++j)
#pragma unroll
      for (int r = 0; r < 4; ++r) {
        int m = m0 + wr * 128 + i * 16 + lg * 4 + r;
        int n = n0 + wc * 64 + j * 16 + l16;
        Cf[(size_t)m * N + n] = acc[i][j][r];
      }
}

// ---------- QKV GEMM: 256x192, BK=64, 8-phase, single-barrier phases ----------
__global__ __launch_bounds__(512) void k_gqkv(const u16* __restrict__ A,
                                              const u16* __restrict__ Bt,
                                              u16* __restrict__ Qb,
                                              u16* __restrict__ Kb,
                                              u16* __restrict__ Vb) {
  __shared__ __align__(16) char smem[114688];
  const int Kd = HID_;
  const int NT = Kd >> 6;

  // grid 32x16 = 512, cpx = 64
  int orig = blockIdx.y * 32 + blockIdx.x;
  int swz = (orig & 7) * 64 + (orig >> 3);
  int bx = swz & 31, by = swz >> 5;
  int m0 = by * 256, n0 = bx * 192;

  int t = threadIdx.x, lane = t & 63, wave = t >> 6;
  int wr = wave >> 2, wc = wave & 3;
  int lg = lane >> 4, l16 = lane & 15;
  int loff = l16 * 64 + ((lg ^ ((l16 >> 1) & 3)) << 4);
  int srow = lane >> 2, schk = (lane & 3) ^ ((lane >> 3) & 3);

  const u16* Asrc = A + (size_t)(m0 + wave * 32 + srow) * Kd + schk * 8;
  const u16* sB0 = Bt + (size_t)(n0 + wave * 16 + srow) * Kd + schk * 8;
  const u16* sB1 = Bt + (size_t)(n0 + 128 + (wave & 3) * 16 + srow) * Kd + schk * 8;
  int bdst2 = (8 + (wave & 3)) << 10;

  f32x4 acc[8][3] = {};

#define QST_A(tile, kc, BB) do {                                              \
    char* d_ = smem + (BB) + ((kc) << 14) + (wave << 11);                     \
    const u16* s_ = Asrc + (size_t)(tile) * 64 + (kc) * 32;                   \
    GLD16(s_, d_); GLD16(s_ + (size_t)16 * Kd, d_ + 1024); } while (0)
#define QST_B(tile, kc, BB) do {                                              \
    char* db_ = smem + (BB) + 32768 + (kc) * 12288;                           \
    GLD16(sB0 + (size_t)(tile) * 64 + (kc) * 32, db_ + (wave << 10));         \
    GLD16(sB1 + (size_t)(tile) * 64 + (kc) * 32, db_ + bdst2); } while (0)
#define QLDB(BB, kc) do { _Pragma("unroll")                                   \
    for (int j = 0; j < 3; ++j)                                               \
      bfr[j] = ldb8b(smem + (BB) + 32768 + (kc) * 12288 + ((wc * 3 + j) << 10) + loff); } while (0)
#define QLDA(BB, kc, mh) do { _Pragma("unroll")                               \
    for (int i = 0; i < 4; ++i)                                               \
      af[i] = ldb8b(smem + (BB) + ((kc) << 14) + ((wr * 8 + (mh) * 4 + i) << 10) + loff); } while (0)
#define QMFMA(mh) do { _Pragma("unroll")                                      \
    for (int i = 0; i < 4; ++i) { _Pragma("unroll")                           \
      for (int j = 0; j < 3; ++j)                                             \
        acc[(mh) * 4 + i][j] = __builtin_amdgcn_mfma_f32_16x16x32_bf16(af[i], bfr[j], acc[(mh) * 4 + i][j], 0, 0, 0); } } while (0)

  QST_A(0, 0, 0); QST_B(0, 0, 0); QST_A(0, 1, 0); QST_B(0, 1, 0);
  QST_A(1, 0, 57344); QST_B(1, 0, 57344);
  VM8; BAR;

  for (int it = 0; it < (NT >> 1); ++it) {
    int a = it << 1;
    bool pf = (a + 2 < NT);
    bf16x8 bfr[3], af[4];
    // P1
    QLDB(0, 0); QLDA(0, 0, 0); QST_A(a + 1, 1, 57344);
    PRIO1; QMFMA(0); PRIO0; BAR;
    // P2
    QLDA(0, 0, 1); QST_B(a + 1, 1, 57344);
    PRIO1; QMFMA(1); PRIO0; if (pf) { VM8; } else { VM0; } BAR;
    // P3
    QLDB(0, 1); QLDA(0, 1, 0); if (pf) QST_A(a + 2, 0, 0);
    PRIO1; QMFMA(0); PRIO0; BAR;
    // P4
    QLDA(0, 1, 1); if (pf) QST_B(a + 2, 0, 0);
    PRIO1; QMFMA(1); PRIO0; if (pf) { VM8; } else { VM0; } BAR;
    // P5
    QLDB(57344, 0); QLDA(57344, 0, 0); if (pf) QST_A(a + 2, 1, 0);
    PRIO1; QMFMA(0); PRIO0; BAR;
    // P6
    QLDA(57344, 0, 1); if (pf) QST_B(a + 2, 1, 0);
    PRIO1; QMFMA(1); PRIO0; if (pf) { VM8; } else { VM0; } BAR;
    // P7
    QLDB(57344, 1); QLDA(57344, 1, 0); if (pf) QST_A(a + 3, 0, 57344);
    PRIO1; QMFMA(0); PRIO0; BAR;
    // P8
    QLDA(57344, 1, 1); if (pf) QST_B(a + 3, 0, 57344);
    PRIO1; QMFMA(1); PRIO0; if (pf) { VM8; } BAR;
  }
#undef QST_A
#undef QST_B
#undef QLDB
#undef QLDA
#undef QMFMA

  // epilogue: per-element head/d (192-wide N slice crosses head boundaries)
#pragma unroll
  for (int i = 0; i < 8; ++i)
#pragma unroll
    for (int j = 0; j < 3; ++j)
#pragma unroll
      for (int r = 0; r < 4; ++r) {
        int m = m0 + wr * 128 + i * 16 + lg * 4 + r;
        int n = n0 + wc * 48 + j * 16 + l16;
        int head = n >> 7, d = n & 127;
        int b = m >> 11, s = m & (S_ - 1);
        u16 val = f2b(acc[i][j][r]);
        if (head < NH_) {
          Qb[(((size_t)b * NH_ + head) * S_ + s) * HD_ + d] = val;
        } else if (head < NH_ + NKV_) {
          Kb[(((size_t)b * NKV_ + (head - NH_)) * S_ + s) * HD_ + d] = val;
        } else {
          Vb[(((size_t)b * NKV_ + (head - NH_ - NKV_)) * HD_ + d) * S_ + s] = val;
        }
      }
}

// ---------- kernel 4: RoPE on K only (Q fused into attention) ----------
__global__ __launch_bounds__(256) void k_ropek(u16* __restrict__ Kb,
                                               const int* __restrict__ pos,
                                               const float* __restrict__ ct,
                                               const float* __restrict__ st) {
  int wave = threadIdx.x >> 6, lane = threadIdx.x & 63;
  int row = blockIdx.x * 4 + wave;   // 0 .. B*NKV*S-1
  int s = row & (S_ - 1);
  int b = row / (NKV_ * S_);
  int p = pos[b * S_ + s];
  size_t base = (size_t)row * HD_;
  float x1 = b2f(Kb[base + lane]);
  float x2 = b2f(Kb[base + 64 + lane]);
  float c  = ct[(size_t)p * HD_ + lane];
  float sn = st[(size_t)p * HD_ + lane];
  Kb[base + lane]      = f2b(x1 * c - x2 * sn);
  Kb[base + 64 + lane] = f2b(x2 * c + x1 * sn);
}

// ---------- kernel 5: causal GQA flash attention + fused Q-RoPE ----------
__global__ __launch_bounds__(256, 4) void k_attn(const u16* __restrict__ Q,
                                                 const u16* __restrict__ K,
                                                 const u16* __restrict__ Vt,
                                                 u16* __restrict__ Ob,
                                                 const int* __restrict__ pos,
                                                 const float* __restrict__ ct,
                                                 const float* __restrict__ st) {
  __shared__ __align__(16) char smem[40960];
  const int VS_OFF = 16384, PS_OFF = 32768;

  int bid = blockIdx.x;
  int pid = bid & 15;
  int h   = (bid >> 4) & 31;
  int b   = bid >> 9;
  int kvh = h >> 2;
  int tid = threadIdx.x;
  int wave = tid >> 6, lane = tid & 63;
  int lg = lane >> 4, l16 = lane & 15;
  int lsw = (l16 & 7) << 4;

  const u16* Qp = Q  + (((size_t)b * NH_  + h)   * S_) * HD_;
  const u16* Kp = K  + (((size_t)b * NKV_ + kvh) * S_) * HD_;
  const u16* Vp = Vt + (((size_t)b * NKV_ + kvh) * HD_) * S_;

  for (int pass = 0; pass < 2; ++pass) {
    int qt = pass ? (31 - pid) : pid;
    int q0 = qt * 64 + wave * 16;
    int qg = q0 + l16;

    u16x8 qu[4];
#pragma unroll
    for (int c = 0; c < 4; ++c)
      qu[c] = *(const u16x8*)&Qp[(size_t)qg * HD_ + c * 32 + lg * 8];
    int prot = pos[b * S_ + qg];
    const float* cb = ct + (size_t)prot * HD_;
    const float* sb = st + (size_t)prot * HD_;
    bf16x8 qf[4];
#pragma unroll
    for (int c = 0; c < 4; ++c) {
      int d0 = c * 32 + lg * 8;
      u16x8 o;
#pragma unroll
      for (int e = 0; e < 8; ++e) {
        float x  = b2f(qu[c][e]);
        float xp = b2f(qu[c ^ 2][e]);
        float cc = cb[d0 + e];
        float ss = sb[d0 + e];
        float res = (c < 2) ? (x * cc - xp * ss) : fmaf(xp, ss, x * cc);
        o[e] = f2b(res);
      }
      qf[c] = __builtin_bit_cast(bf16x8, o);
    }

    f32x4 oacc[8] = {};
    float mrun = -1e30f, lrun = 0.f;

    int nt = qt + 1;
    for (int tI = 0; tI < nt; ++tI) {
      int kb = tI * 64;
      __syncthreads();
#pragma unroll
      for (int i = 0; i < 4; ++i) {
        int ci = i * 256 + tid;
        int r = ci >> 4, ch = ci & 15;
        u16x8 v = *(const u16x8*)&Kp[(size_t)(kb + r) * HD_ + ch * 8];
        *(u16x8*)(smem + r * 256 + ((ch * 16) ^ ((r & 7) << 4))) = v;
      }
#pragma unroll
      for (int i = 0; i < 4; ++i) {
        int ci = i * 256 + tid;
        int r = ci >> 3, ch = ci & 7;
        u16x8 v = *(const u16x8*)&Vp[(size_t)r * S_ + kb + ch * 8];
        *(u16x8*)(smem + VS_OFF + r * 128 + ((ch * 16) ^ ((r & 7) << 4))) = v;
      }
      __syncthreads();

      f32x4 sc[4] = {};
#pragma unroll
      for (int c = 0; c < 4; ++c) {
#pragma unroll
        for (int n = 0; n < 4; ++n) {
          bf16x8 kf = ldb8b(smem + (n * 16 + l16) * 256 + ((c * 64 + lg * 16) ^ lsw));
          sc[n] = __builtin_amdgcn_mfma_f32_16x16x32_bf16(kf, qf[c], sc[n], 0, 0, 0);
        }
      }

      bool diag = (tI == qt);
      float mx = -1e30f;
#pragma unroll
      for (int n = 0; n < 4; ++n)
#pragma unroll
        for (int r = 0; r < 4; ++r) {
          float v = sc[n][r];
          int key = kb + n * 16 + lg * 4 + r;
          if (diag && key > qg) v = -1e30f;
          sc[n][r] = v;
          mx = fmaxf(mx, v);
        }
      mx = fmaxf(mx, __shfl_xor(mx, 16));
      mx = fmaxf(mx, __shfl_xor(mx, 32));
      float mnew = fmaxf(mrun, mx * SCALE_);
      float alpha = __expf(mrun - mnew);
      float ps = 0.f;
#pragma unroll
      for (int n = 0; n < 4; ++n) {
        u16x4 pk;
#pragma unroll
        for (int r = 0; r < 4; ++r) {
          float p = __expf(fmaf(sc[n][r], SCALE_, -mnew));
          ps += p;
          pk[r] = f2b(p);
        }
        *(u16x4*)(smem + PS_OFF + wave * 2048 + l16 * 128 + ((n * 32 + lg * 8) ^ lsw)) = pk;
      }
      ps += __shfl_xor(ps, 16);
      ps += __shfl_xor(ps, 32);
      lrun = lrun * alpha + ps;
      mrun = mnew;

      float ar[4];
#pragma unroll
      for (int r = 0; r < 4; ++r) ar[r] = __shfl(alpha, lg * 4 + r);
#pragma unroll
      for (int ns = 0; ns < 8; ++ns)
#pragma unroll
        for (int r = 0; r < 4; ++r) oacc[ns][r] *= ar[r];

#pragma unroll
      for (int ck = 0; ck < 2; ++ck) {
        bf16x8 pa = ldb8b(smem + PS_OFF + wave * 2048 + l16 * 128 + ((ck * 64 + lg * 16) ^ lsw));
#pragma unroll
        for (int ns = 0; ns < 8; ++ns) {
          bf16x8 vf = ldb8b(smem + VS_OFF + (ns * 16 + l16) * 128 + ((ck * 64 + lg * 16) ^ lsw));
          oacc[ns] = __builtin_amdgcn_mfma_f32_16x16x32_bf16(pa, vf, oacc[ns], 0, 0, 0);
        }
      }
    }

    float lr[4];
#pragma unroll
    for (int r = 0; r < 4; ++r) lr[r] = 1.0f / __shfl(lrun, lg * 4 + r);
#pragma unroll
    for (int ns = 0; ns < 8; ++ns)
#pragma unroll
      for (int r = 0; r < 4; ++r) {
        int q = q0 + lg * 4 + r;
        Ob[((size_t)(b * S_) + q) * (NH_ * HD_) + h * HD_ + ns * 16 + l16] =
            f2b(oacc[ns][r] * lr[r]);
      }
  }
}

// ---------- launch ----------
extern "C" void kernel_launch(void* const* d_in, const int* in_sizes, int n_in,
                              void* d_out, int out_size, void* d_ws, size_t ws_size,
                              hipStream_t stream) {
  const float* hs  = (const float*)d_in[0];
  const int*   pos = (const int*)d_in[1];
  const float* ct  = (const float*)d_in[2];
  const float* st  = (const float*)d_in[3];
  const float* Wq  = (const float*)d_in[4];
  const float* Wk  = (const float*)d_in[5];
  const float* Wv  = (const float*)d_in[6];
  const float* Wo  = (const float*)d_in[7];
  float* out = (float*)d_out;

  char* w = (char*)d_ws;
  u16* Xb    = (u16*)(w);                       // [4096][4096]
  u16* WqkvT = (u16*)(w + 33554432ull);         // [6144][4096]
  u16* WoT   = (u16*)(w + 83886080ull);         // [4096][4096]
  u16* Qb    = (u16*)(w + 117440512ull);        // [2][32][2048][128]
  u16* Kb    = (u16*)(w + 150994944ull);        // [2][8][2048][128]
  u16* Vb    = (u16*)(w + 159383552ull);        // [2][8][128][2048]
  u16* Attb  = (u16*)(w + 167772160ull);        // [4096][4096]

  k_prep<<<26624, 256, 0, stream>>>(hs, Xb, Wq, Wk, Wv, WqkvT, Wo, WoT);
  k_gqkv<<<dim3(32, 16), 512, 0, stream>>>(Xb, WqkvT, Qb, Kb, Vb);
  k_ropek<<<8192, 256, 0, stream>>>(Kb, pos, ct, st);
  k_attn<<<1024, 256, 0, stream>>>(Qb, Kb, Vb, Attb, pos, ct, st);
  k_gemm_out<<<dim3(16, 16), 512, 0, stream>>>(Attb, WoT, out, 4096, 4096, 4096);
}

// Round 18
// 589.540 us; speedup vs baseline: 1.0474x; 1.0025x over previous
//
#include <hip/hip_runtime.h>
#include <stdint.h>

typedef unsigned short u16;
typedef __bf16 bf16x8 __attribute__((ext_vector_type(8)));
typedef unsigned short u16x8 __attribute__((ext_vector_type(8)));
typedef unsigned short u16x4 __attribute__((ext_vector_type(4)));
typedef float f32x4 __attribute__((ext_vector_type(4)));

#define B_ 2
#define S_ 2048
#define HID_ 4096
#define NH_ 32
#define NKV_ 8
#define HD_ 128
#define NTOT_ 6144
#define SCALE_ 0.08838834764831845f

#define GLD16(gp, lp)                                                     \
  __builtin_amdgcn_global_load_lds(                                       \
      (__attribute__((address_space(1))) void*)(gp),                      \
      (__attribute__((address_space(3))) void*)(lp), 16, 0, 0)

#define BAR __builtin_amdgcn_s_barrier()
#define PRIO1 __builtin_amdgcn_s_setprio(1)
#define PRIO0 __builtin_amdgcn_s_setprio(0)
#define VM8 asm volatile("s_waitcnt vmcnt(8)" ::: "memory")
#define VM0 asm volatile("s_waitcnt vmcnt(0)" ::: "memory")

// ---------- bf16 helpers ----------
__device__ __forceinline__ u16 f2b(float f) {
  union { float f; uint32_t u; } v; v.f = f;
  uint32_t u = v.u;
  u = u + 0x7fffu + ((u >> 16) & 1u);
  return (u16)(u >> 16);
}
__device__ __forceinline__ float b2f(u16 s) {
  union { uint32_t u; float f; } v; v.u = ((uint32_t)s) << 16;
  return v.f;
}
__device__ __forceinline__ bf16x8 ldb8(const u16* p) {
  u16x8 u = *(const u16x8*)p;
  return __builtin_bit_cast(bf16x8, u);
}
__device__ __forceinline__ bf16x8 ldb8b(const char* p) {
  u16x8 u = *(const u16x8*)p;
  return __builtin_bit_cast(bf16x8, u);
}

// ---------- merged prep kernel: convx + convqkv + convT(Wo) in one launch ----------
__global__ __launch_bounds__(256) void k_prep(const float* __restrict__ hs,
                                              u16* __restrict__ Xb,
                                              const float* __restrict__ Wq,
                                              const float* __restrict__ Wk,
                                              const float* __restrict__ Wv,
                                              u16* __restrict__ WqkvT,
                                              const float* __restrict__ Wo,
                                              u16* __restrict__ WoT) {
  __shared__ u16 tile[64][65];
  int bid = blockIdx.x;
  int t = threadIdx.x;
  if (bid < 16384) {
    int i = bid * 256 + t;
    const float4 v = ((const float4*)hs)[i];
    u16x4 o = { f2b(v.x), f2b(v.y), f2b(v.z), f2b(v.w) };
    *(u16x4*)(Xb + (size_t)i * 4) = o;
    return;
  }
  const float* src;
  u16* dst;
  int N, ns, ng, k0;
  const int Kd = HID_;
  if (bid < 16384 + 6144) {
    int ti = bid - 16384;
    k0 = (ti & 63) * 64;
    ng = (ti >> 6) * 64;
    dst = WqkvT;
    if (ng < 4096)      { src = Wq; N = 4096; ns = ng; }
    else if (ng < 5120) { src = Wk; N = 1024; ns = ng - 4096; }
    else                { src = Wv; N = 1024; ns = ng - 5120; }
  } else {
    int ti = bid - 16384 - 6144;
    k0 = (ti & 63) * 64;
    ng = (ti >> 6) * 64;
    src = Wo; dst = WoT; N = 4096; ns = ng;
  }
  int rr = t >> 4;
  int cc = (t & 15) * 4;
#pragma unroll
  for (int p = 0; p < 4; ++p) {
    int r = p * 16 + rr;
    float4 v = *(const float4*)&src[(size_t)(k0 + r) * N + ns + cc];
    tile[cc + 0][r] = f2b(v.x);
    tile[cc + 1][r] = f2b(v.y);
    tile[cc + 2][r] = f2b(v.z);
    tile[cc + 3][r] = f2b(v.w);
  }
  __syncthreads();
#pragma unroll
  for (int p = 0; p < 4; ++p) {
    int n = p * 16 + rr;
    u16x4 o = { tile[n][cc], tile[n][cc + 1], tile[n][cc + 2], tile[n][cc + 3] };
    *(u16x4*)&dst[(size_t)(ng + n) * Kd + k0 + cc] = o;
  }
}

// ---------- out-proj GEMM: 256x256, BK=64, 8-phase, barriers at even phases only ----------
// R18: sync = VM8/VM0 + BAR at even-phase ends only (4 per 2 K-tiles).
// RAW: per-wave VM8 cadence unchanged (queue 8->12->8); each even-end VM8
// retires exactly the 4 loads read in the next two phases; the BAR makes them
// visible. WAR: barrier semantics bound drift -- a wave at odd phase p+1
// implies all waves passed the preceding even BAR, hence the overwritten
// region's reads (>=2 phases earlier) are lgkm-serviced. Tails VM0/empty.
__global__ __launch_bounds__(512) void k_gemm_out(const u16* __restrict__ A,
                                                  const u16* __restrict__ Bt,
                                                  float* __restrict__ Cf,
                                                  int M, int N, int Kd) {
  __shared__ __align__(16) char smem[131072];
  const int NT = Kd >> 6;

  int nwg = gridDim.x * gridDim.y;
  int orig = blockIdx.y * gridDim.x + blockIdx.x;
  int cpx = nwg >> 3;
  int swz = (orig & 7) * cpx + (orig >> 3);
  int bx = swz % gridDim.x, by = swz / gridDim.x;
  int m0 = by * 256, n0 = bx * 256;

  int t = threadIdx.x, lane = t & 63, wave = t >> 6;
  int wr = wave >> 2, wc = wave & 3;
  int lg = lane >> 4, l16 = lane & 15;
  int loff = l16 * 64 + ((lg ^ ((l16 >> 1) & 3)) << 4);
  int srow = lane >> 2, schk = (lane & 3) ^ ((lane >> 3) & 3);

  const u16* Asrc = A  + (size_t)(m0 + wave * 32 + srow) * Kd + schk * 8;
  const u16* Bsrc = Bt + (size_t)(n0 + wave * 32 + srow) * Kd + schk * 8;

  f32x4 acc[8][4] = {};

#define OST_A(tile, kc, BB) do {                                              \
    char* d_ = smem + (BB) + ((kc) << 14) + (wave << 11);                     \
    const u16* s_ = Asrc + (size_t)(tile) * 64 + (kc) * 32;                   \
    GLD16(s_, d_); GLD16(s_ + (size_t)16 * Kd, d_ + 1024); } while (0)
#define OST_B(tile, kc, BB) do {                                              \
    char* d_ = smem + (BB) + 32768 + ((kc) << 14) + (wave << 11);             \
    const u16* s_ = Bsrc + (size_t)(tile) * 64 + (kc) * 32;                   \
    GLD16(s_, d_); GLD16(s_ + (size_t)16 * Kd, d_ + 1024); } while (0)
#define OLDB(BB, kc) do { _Pragma("unroll")                                   \
    for (int j = 0; j < 4; ++j)                                               \
      bfr[j] = ldb8b(smem + (BB) + 32768 + ((kc) << 14) + ((wc * 4 + j) << 10) + loff); } while (0)
#define OLDA(BB, kc, mh) do { _Pragma("unroll")                               \
    for (int i = 0; i < 4; ++i)                                               \
      af[i] = ldb8b(smem + (BB) + ((kc) << 14) + ((wr * 8 + (mh) * 4 + i) << 10) + loff); } while (0)
#define OMFMA(mh) do { _Pragma("unroll")                                      \
    for (int i = 0; i < 4; ++i) { _Pragma("unroll")                           \
      for (int j = 0; j < 4; ++j)                                             \
        acc[(mh) * 4 + i][j] = __builtin_amdgcn_mfma_f32_16x16x32_bf16(af[i], bfr[j], acc[(mh) * 4 + i][j], 0, 0, 0); } } while (0)

  OST_A(0, 0, 0); OST_B(0, 0, 0); OST_A(0, 1, 0); OST_B(0, 1, 0);
  OST_A(1, 0, 65536); OST_B(1, 0, 65536);
  VM8; BAR;

  for (int it = 0; it < (NT >> 1); ++it) {
    int a = it << 1;
    bool pf = (a + 2 < NT);
    bf16x8 bfr[4], af[4];
    // P1 (no barrier)
    OLDB(0, 0); OLDA(0, 0, 0); OST_A(a + 1, 1, 65536);
    PRIO1; OMFMA(0); PRIO0;
    // P2 (sync)
    OLDA(0, 0, 1); OST_B(a + 1, 1, 65536);
    PRIO1; OMFMA(1); PRIO0; if (pf) { VM8; } else { VM0; } BAR;
    // P3 (no barrier)
    OLDB(0, 1); OLDA(0, 1, 0); if (pf) OST_A(a + 2, 0, 0);
    PRIO1; OMFMA(0); PRIO0;
    // P4 (sync)
    OLDA(0, 1, 1); if (pf) OST_B(a + 2, 0, 0);
    PRIO1; OMFMA(1); PRIO0; if (pf) { VM8; } else { VM0; } BAR;
    // P5 (no barrier)
    OLDB(65536, 0); OLDA(65536, 0, 0); if (pf) OST_A(a + 2, 1, 0);
    PRIO1; OMFMA(0); PRIO0;
    // P6 (sync)
    OLDA(65536, 0, 1); if (pf) OST_B(a + 2, 1, 0);
    PRIO1; OMFMA(1); PRIO0; if (pf) { VM8; } else { VM0; } BAR;
    // P7 (no barrier)
    OLDB(65536, 1); OLDA(65536, 1, 0); if (pf) OST_A(a + 3, 0, 65536);
    PRIO1; OMFMA(0); PRIO0;
    // P8 (sync)
    OLDA(65536, 1, 1); if (pf) OST_B(a + 3, 0, 65536);
    PRIO1; OMFMA(1); PRIO0; if (pf) { VM8; } BAR;
  }
#undef OST_A
#undef OST_B
#undef OLDB
#undef OLDA
#undef OMFMA

#pragma unroll
  for (int i = 0; i < 8; ++i)
#pragma unroll
    for (int j = 0; j < 4; ++j)
#pragma unroll
      for (int r = 0; r < 4; ++r) {
        int m = m0 + wr * 128 + i * 16 + lg * 4 + r;
        int n = n0 + wc * 64 + j * 16 + l16;
        Cf[(size_t)m * N + n] = acc[i][j][r];
      }
}

// ---------- QKV GEMM: 256x192, BK=64, 8-phase, barriers at even phases only ----------
__global__ __launch_bounds__(512) void k_gqkv(const u16* __restrict__ A,
                                              const u16* __restrict__ Bt,
                                              u16* __restrict__ Qb,
                                              u16* __restrict__ Kb,
                                              u16* __restrict__ Vb) {
  __shared__ __align__(16) char smem[114688];
  const int Kd = HID_;
  const int NT = Kd >> 6;

  // grid 32x16 = 512, cpx = 64
  int orig = blockIdx.y * 32 + blockIdx.x;
  int swz = (orig & 7) * 64 + (orig >> 3);
  int bx = swz & 31, by = swz >> 5;
  int m0 = by * 256, n0 = bx * 192;

  int t = threadIdx.x, lane = t & 63, wave = t >> 6;
  int wr = wave >> 2, wc = wave & 3;
  int lg = lane >> 4, l16 = lane & 15;
  int loff = l16 * 64 + ((lg ^ ((l16 >> 1) & 3)) << 4);
  int srow = lane >> 2, schk = (lane & 3) ^ ((lane >> 3) & 3);

  const u16* Asrc = A + (size_t)(m0 + wave * 32 + srow) * Kd + schk * 8;
  const u16* sB0 = Bt + (size_t)(n0 + wave * 16 + srow) * Kd + schk * 8;
  const u16* sB1 = Bt + (size_t)(n0 + 128 + (wave & 3) * 16 + srow) * Kd + schk * 8;
  int bdst2 = (8 + (wave & 3)) << 10;

  f32x4 acc[8][3] = {};

#define QST_A(tile, kc, BB) do {                                              \
    char* d_ = smem + (BB) + ((kc) << 14) + (wave << 11);                     \
    const u16* s_ = Asrc + (size_t)(tile) * 64 + (kc) * 32;                   \
    GLD16(s_, d_); GLD16(s_ + (size_t)16 * Kd, d_ + 1024); } while (0)
#define QST_B(tile, kc, BB) do {                                              \
    char* db_ = smem + (BB) + 32768 + (kc) * 12288;                           \
    GLD16(sB0 + (size_t)(tile) * 64 + (kc) * 32, db_ + (wave << 10));         \
    GLD16(sB1 + (size_t)(tile) * 64 + (kc) * 32, db_ + bdst2); } while (0)
#define QLDB(BB, kc) do { _Pragma("unroll")                                   \
    for (int j = 0; j < 3; ++j)                                               \
      bfr[j] = ldb8b(smem + (BB) + 32768 + (kc) * 12288 + ((wc * 3 + j) << 10) + loff); } while (0)
#define QLDA(BB, kc, mh) do { _Pragma("unroll")                               \
    for (int i = 0; i < 4; ++i)                                               \
      af[i] = ldb8b(smem + (BB) + ((kc) << 14) + ((wr * 8 + (mh) * 4 + i) << 10) + loff); } while (0)
#define QMFMA(mh) do { _Pragma("unroll")                                      \
    for (int i = 0; i < 4; ++i) { _Pragma("unroll")                           \
      for (int j = 0; j < 3; ++j)                                             \
        acc[(mh) * 4 + i][j] = __builtin_amdgcn_mfma_f32_16x16x32_bf16(af[i], bfr[j], acc[(mh) * 4 + i][j], 0, 0, 0); } } while (0)

  QST_A(0, 0, 0); QST_B(0, 0, 0); QST_A(0, 1, 0); QST_B(0, 1, 0);
  QST_A(1, 0, 57344); QST_B(1, 0, 57344);
  VM8; BAR;

  for (int it = 0; it < (NT >> 1); ++it) {
    int a = it << 1;
    bool pf = (a + 2 < NT);
    bf16x8 bfr[3], af[4];
    // P1 (no barrier)
    QLDB(0, 0); QLDA(0, 0, 0); QST_A(a + 1, 1, 57344);
    PRIO1; QMFMA(0); PRIO0;
    // P2 (sync)
    QLDA(0, 0, 1); QST_B(a + 1, 1, 57344);
    PRIO1; QMFMA(1); PRIO0; if (pf) { VM8; } else { VM0; } BAR;
    // P3 (no barrier)
    QLDB(0, 1); QLDA(0, 1, 0); if (pf) QST_A(a + 2, 0, 0);
    PRIO1; QMFMA(0); PRIO0;
    // P4 (sync)
    QLDA(0, 1, 1); if (pf) QST_B(a + 2, 0, 0);
    PRIO1; QMFMA(1); PRIO0; if (pf) { VM8; } else { VM0; } BAR;
    // P5 (no barrier)
    QLDB(57344, 0); QLDA(57344, 0, 0); if (pf) QST_A(a + 2, 1, 0);
    PRIO1; QMFMA(0); PRIO0;
    // P6 (sync)
    QLDA(57344, 0, 1); if (pf) QST_B(a + 2, 1, 0);
    PRIO1; QMFMA(1); PRIO0; if (pf) { VM8; } else { VM0; } BAR;
    // P7 (no barrier)
    QLDB(57344, 1); QLDA(57344, 1, 0); if (pf) QST_A(a + 3, 0, 57344);
    PRIO1; QMFMA(0); PRIO0;
    // P8 (sync)
    QLDA(57344, 1, 1); if (pf) QST_B(a + 3, 0, 57344);
    PRIO1; QMFMA(1); PRIO0; if (pf) { VM8; } BAR;
  }
#undef QST_A
#undef QST_B
#undef QLDB
#undef QLDA
#undef QMFMA

  // epilogue: per-element head/d (192-wide N slice crosses head boundaries)
#pragma unroll
  for (int i = 0; i < 8; ++i)
#pragma unroll
    for (int j = 0; j < 3; ++j)
#pragma unroll
      for (int r = 0; r < 4; ++r) {
        int m = m0 + wr * 128 + i * 16 + lg * 4 + r;
        int n = n0 + wc * 48 + j * 16 + l16;
        int head = n >> 7, d = n & 127;
        int b = m >> 11, s = m & (S_ - 1);
        u16 val = f2b(acc[i][j][r]);
        if (head < NH_) {
          Qb[(((size_t)b * NH_ + head) * S_ + s) * HD_ + d] = val;
        } else if (head < NH_ + NKV_) {
          Kb[(((size_t)b * NKV_ + (head - NH_)) * S_ + s) * HD_ + d] = val;
        } else {
          Vb[(((size_t)b * NKV_ + (head - NH_ - NKV_)) * HD_ + d) * S_ + s] = val;
        }
      }
}

// ---------- kernel 4: RoPE on K only (Q fused into attention) ----------
__global__ __launch_bounds__(256) void k_ropek(u16* __restrict__ Kb,
                                               const int* __restrict__ pos,
                                               const float* __restrict__ ct,
                                               const float* __restrict__ st) {
  int wave = threadIdx.x >> 6, lane = threadIdx.x & 63;
  int row = blockIdx.x * 4 + wave;   // 0 .. B*NKV*S-1
  int s = row & (S_ - 1);
  int b = row / (NKV_ * S_);
  int p = pos[b * S_ + s];
  size_t base = (size_t)row * HD_;
  float x1 = b2f(Kb[base + lane]);
  float x2 = b2f(Kb[base + 64 + lane]);
  float c  = ct[(size_t)p * HD_ + lane];
  float sn = st[(size_t)p * HD_ + lane];
  Kb[base + lane]      = f2b(x1 * c - x2 * sn);
  Kb[base + 64 + lane] = f2b(x2 * c + x1 * sn);
}

// ---------- kernel 5: causal GQA flash attention + fused Q-RoPE ----------
__global__ __launch_bounds__(256, 4) void k_attn(const u16* __restrict__ Q,
                                                 const u16* __restrict__ K,
                                                 const u16* __restrict__ Vt,
                                                 u16* __restrict__ Ob,
                                                 const int* __restrict__ pos,
                                                 const float* __restrict__ ct,
                                                 const float* __restrict__ st) {
  __shared__ __align__(16) char smem[40960];
  const int VS_OFF = 16384, PS_OFF = 32768;

  int bid = blockIdx.x;
  int pid = bid & 15;
  int h   = (bid >> 4) & 31;
  int b   = bid >> 9;
  int kvh = h >> 2;
  int tid = threadIdx.x;
  int wave = tid >> 6, lane = tid & 63;
  int lg = lane >> 4, l16 = lane & 15;
  int lsw = (l16 & 7) << 4;

  const u16* Qp = Q  + (((size_t)b * NH_  + h)   * S_) * HD_;
  const u16* Kp = K  + (((size_t)b * NKV_ + kvh) * S_) * HD_;
  const u16* Vp = Vt + (((size_t)b * NKV_ + kvh) * HD_) * S_;

  for (int pass = 0; pass < 2; ++pass) {
    int qt = pass ? (31 - pid) : pid;
    int q0 = qt * 64 + wave * 16;
    int qg = q0 + l16;

    u16x8 qu[4];
#pragma unroll
    for (int c = 0; c < 4; ++c)
      qu[c] = *(const u16x8*)&Qp[(size_t)qg * HD_ + c * 32 + lg * 8];
    int prot = pos[b * S_ + qg];
    const float* cb = ct + (size_t)prot * HD_;
    const float* sb = st + (size_t)prot * HD_;
    bf16x8 qf[4];
#pragma unroll
    for (int c = 0; c < 4; ++c) {
      int d0 = c * 32 + lg * 8;
      u16x8 o;
#pragma unroll
      for (int e = 0; e < 8; ++e) {
        float x  = b2f(qu[c][e]);
        float xp = b2f(qu[c ^ 2][e]);
        float cc = cb[d0 + e];
        float ss = sb[d0 + e];
        float res = (c < 2) ? (x * cc - xp * ss) : fmaf(xp, ss, x * cc);
        o[e] = f2b(res);
      }
      qf[c] = __builtin_bit_cast(bf16x8, o);
    }

    f32x4 oacc[8] = {};
    float mrun = -1e30f, lrun = 0.f;

    int nt = qt + 1;
    for (int tI = 0; tI < nt; ++tI) {
      int kb = tI * 64;
      __syncthreads();
#pragma unroll
      for (int i = 0; i < 4; ++i) {
        int ci = i * 256 + tid;
        int r = ci >> 4, ch = ci & 15;
        u16x8 v = *(const u16x8*)&Kp[(size_t)(kb + r) * HD_ + ch * 8];
        *(u16x8*)(smem + r * 256 + ((ch * 16) ^ ((r & 7) << 4))) = v;
      }
#pragma unroll
      for (int i = 0; i < 4; ++i) {
        int ci = i * 256 + tid;
        int r = ci >> 3, ch = ci & 7;
        u16x8 v = *(const u16x8*)&Vp[(size_t)r * S_ + kb + ch * 8];
        *(u16x8*)(smem + VS_OFF + r * 128 + ((ch * 16) ^ ((r & 7) << 4))) = v;
      }
      __syncthreads();

      f32x4 sc[4] = {};
#pragma unroll
      for (int c = 0; c < 4; ++c) {
#pragma unroll
        for (int n = 0; n < 4; ++n) {
          bf16x8 kf = ldb8b(smem + (n * 16 + l16) * 256 + ((c * 64 + lg * 16) ^ lsw));
          sc[n] = __builtin_amdgcn_mfma_f32_16x16x32_bf16(kf, qf[c], sc[n], 0, 0, 0);
        }
      }

      bool diag = (tI == qt);
      float mx = -1e30f;
#pragma unroll
      for (int n = 0; n < 4; ++n)
#pragma unroll
        for (int r = 0; r < 4; ++r) {
          float v = sc[n][r];
          int key = kb + n * 16 + lg * 4 + r;
          if (diag && key > qg) v = -1e30f;
          sc[n][r] = v;
          mx = fmaxf(mx, v);
        }
      mx = fmaxf(mx, __shfl_xor(mx, 16));
      mx = fmaxf(mx, __shfl_xor(mx, 32));
      float mnew = fmaxf(mrun, mx * SCALE_);
      float alpha = __expf(mrun - mnew);
      float ps = 0.f;
#pragma unroll
      for (int n = 0; n < 4; ++n) {
        u16x4 pk;
#pragma unroll
        for (int r = 0; r < 4; ++r) {
          float p = __expf(fmaf(sc[n][r], SCALE_, -mnew));
          ps += p;
          pk[r] = f2b(p);
        }
        *(u16x4*)(smem + PS_OFF + wave * 2048 + l16 * 128 + ((n * 32 + lg * 8) ^ lsw)) = pk;
      }
      ps += __shfl_xor(ps, 16);
      ps += __shfl_xor(ps, 32);
      lrun = lrun * alpha + ps;
      mrun = mnew;

      float ar[4];
#pragma unroll
      for (int r = 0; r < 4; ++r) ar[r] = __shfl(alpha, lg * 4 + r);
#pragma unroll
      for (int ns = 0; ns < 8; ++ns)
#pragma unroll
        for (int r = 0; r < 4; ++r) oacc[ns][r] *= ar[r];

#pragma unroll
      for (int ck = 0; ck < 2; ++ck) {
        bf16x8 pa = ldb8b(smem + PS_OFF + wave * 2048 + l16 * 128 + ((ck * 64 + lg * 16) ^ lsw));
#pragma unroll
        for (int ns = 0; ns < 8; ++ns) {
          bf16x8 vf = ldb8b(smem + VS_OFF + (ns * 16 + l16) * 128 + ((ck * 64 + lg * 16) ^ lsw));
          oacc[ns] = __builtin_amdgcn_mfma_f32_16x16x32_bf16(pa, vf, oacc[ns], 0, 0, 0);
        }
      }
    }

    float lr[4];
#pragma unroll
    for (int r = 0; r < 4; ++r) lr[r] = 1.0f / __shfl(lrun, lg * 4 + r);
#pragma unroll
    for (int ns = 0; ns < 8; ++ns)
#pragma unroll
      for (int r = 0; r < 4; ++r) {
        int q = q0 + lg * 4 + r;
        Ob[((size_t)(b * S_) + q) * (NH_ * HD_) + h * HD_ + ns * 16 + l16] =
            f2b(oacc[ns][r] * lr[r]);
      }
  }
}

// ---------- launch ----------
extern "C" void kernel_launch(void* const* d_in, const int* in_sizes, int n_in,
                              void* d_out, int out_size, void* d_ws, size_t ws_size,
                              hipStream_t stream) {
  const float* hs  = (const float*)d_in[0];
  const int*   pos = (const int*)d_in[1];
  const float* ct  = (const float*)d_in[2];
  const float* st  = (const float*)d_in[3];
  const float* Wq  = (const float*)d_in[4];
  const float* Wk  = (const float*)d_in[5];
  const float* Wv  = (const float*)d_in[6];
  const float* Wo  = (const float*)d_in[7];
  float* out = (float*)d_out;

  char* w = (char*)d_ws;
  u16* Xb    = (u16*)(w);                       // [4096][4096]
  u16* WqkvT = (u16*)(w + 33554432ull);         // [6144][4096]
  u16* WoT   = (u16*)(w + 83886080ull);         // [4096][4096]
  u16* Qb    = (u16*)(w + 117440512ull);        // [2][32][2048][128]
  u16* Kb    = (u16*)(w + 150994944ull);        // [2][8][2048][128]
  u16* Vb    = (u16*)(w + 159383552ull);        // [2][8][128][2048]
  u16* Attb  = (u16*)(w + 167772160ull);        // [4096][4096]

  k_prep<<<26624, 256, 0, stream>>>(hs, Xb, Wq, Wk, Wv, WqkvT, Wo, WoT);
  k_gqkv<<<dim3(32, 16), 512, 0, stream>>>(Xb, WqkvT, Qb, Kb, Vb);
  k_ropek<<<8192, 256, 0, stream>>>(Kb, pos, ct, st);
  k_attn<<<1024, 256, 0, stream>>>(Qb, Kb, Vb, Attb, pos, ct, st);
  k_gemm_out<<<dim3(16, 16), 512, 0, stream>>>(Attb, WoT, out, 4096, 4096, 4096);
}